// Round 7
// baseline (454.676 us; speedup 1.0000x reference)
//
#include <hip/hip_runtime.h>
#include <stdint.h>

#define BT_ 16384   // B*T
#define TT  1024
#define CHUNKS 32
#define CLEN   32
#define LANES  16384  // E*B*D

typedef __bf16 bf16x8 __attribute__((ext_vector_type(8)));
typedef float  f32x4  __attribute__((ext_vector_type(4)));
typedef unsigned int u32x4 __attribute__((ext_vector_type(4)));
typedef unsigned int u32x2 __attribute__((ext_vector_type(2)));
typedef unsigned short u16;

__device__ __forceinline__ float b2f(u16 s){
    union { float f; unsigned int u; } c; c.u = ((unsigned int)s) << 16; return c.f;
}
__device__ __forceinline__ u16 f2b(float f){
    union { float f; unsigned int u; } c; c.f = f;
    unsigned int u = c.u;
    return (u16)((u + 0x7fffu + ((u >> 16) & 1u)) >> 16);
}

// async global->LDS, 16 B per lane; LDS dest is wave-uniform base + lane*16
__device__ __forceinline__ void gload_lds16(const u16* g, u16* lds){
    __builtin_amdgcn_global_load_lds(
        (const __attribute__((address_space(1))) void*)g,
        (__attribute__((address_space(3))) void*)lds, 16, 0, 0);
}

// ---------------------------------------------------------------------------
// x: fp32 -> bf16 (A operand of in_proj), 8 elems/thread, 16B stores
// ---------------------------------------------------------------------------
__global__ __launch_bounds__(256) void conv_k(const float* __restrict__ x, u16* __restrict__ xc)
{
    long i = ((long)blockIdx.x * 256 + threadIdx.x) * 8;   // < 4,194,304
    float4 v0 = *reinterpret_cast<const float4*>(x + i);
    float4 v1 = *reinterpret_cast<const float4*>(x + i + 4);
    union { u16 s[8]; u32x4 v; } p;
    p.s[0] = f2b(v0.x); p.s[1] = f2b(v0.y); p.s[2] = f2b(v0.z); p.s[3] = f2b(v0.w);
    p.s[4] = f2b(v1.x); p.s[5] = f2b(v1.y); p.s[6] = f2b(v1.z); p.s[7] = f2b(v1.w);
    *reinterpret_cast<u32x4*>(xc + i) = p.v;
}

// ---------------------------------------------------------------------------
// Weight prep: fp32 -> bf16, TRANSPOSED to [n][k].
// 28 source matrices of 256x256 ([i][o], o contiguous):
//   w in [0,12)  : in_proj (z=k3*4+e)      -> c_ipw_t + w*65536          , ostride 256
//   w in [12,20) : mid (c=(w-12)>>2,e=&3)  -> buf_mw_t + e*131072 + c*256, ostride 512, sign -1 for c=1
//   w in [20,24) : ff_w1 (e)               -> c_fw1_t + e*65536          , ostride 256
//   w in [24,28) : ff_w2 (e)               -> c_fw2_t + e*65536          , ostride 256
// ---------------------------------------------------------------------------
__global__ __launch_bounds__(256) void prep_w(
    const float* __restrict__ ipw, const float* __restrict__ mw,
    const float* __restrict__ fw1, const float* __restrict__ fw2,
    u16* __restrict__ d_ipw, u16* __restrict__ d_mw,
    u16* __restrict__ d_fw1, u16* __restrict__ d_fw2)
{
    __shared__ u16 tile[64][72];
    int blk = blockIdx.x;            // < 448
    int w = blk >> 4, t = blk & 15;
    int tr = (t >> 2) * 64;          // i origin
    int tc = (t & 3) * 64;           // o origin
    const float* src; u16* dst; int ostride; float sign = 1.f;
    if (w < 12)      { src = ipw + (size_t)w * 65536; dst = d_ipw + (size_t)w * 65536; ostride = 256; }
    else if (w < 20) { int u = w - 12, c = u >> 2, e = u & 3;
                       src = mw + (size_t)u * 65536;
                       dst = d_mw + (size_t)e * 131072 + c * 256; ostride = 512;
                       if (c) sign = -1.f; }
    else if (w < 24) { int e = w - 20; src = fw1 + (size_t)e * 65536; dst = d_fw1 + (size_t)e * 65536; ostride = 256; }
    else             { int e = w - 24; src = fw2 + (size_t)e * 65536; dst = d_fw2 + (size_t)e * 65536; ostride = 256; }

    int q = threadIdx.x;
    int r = q >> 2, cb = (q & 3) * 16;
#pragma unroll
    for (int j = 0; j < 4; j++) {
        int col = cb + j * 4;
        const float4 v = *reinterpret_cast<const float4*>(src + (size_t)(tr + r) * 256 + tc + col);
        tile[r][col + 0] = f2b(v.x * sign);
        tile[r][col + 1] = f2b(v.y * sign);
        tile[r][col + 2] = f2b(v.z * sign);
        tile[r][col + 3] = f2b(v.w * sign);
    }
    __syncthreads();
    int ol = q >> 2, ib = (q & 3) * 16;
    union { u16 s[8]; u32x4 v; } p0, p1;
#pragma unroll
    for (int k = 0; k < 8; k++) { p0.s[k] = tile[ib + k][ol]; p1.s[k] = tile[ib + 8 + k][ol]; }
    u16* drow = dst + (size_t)(tc + ol) * ostride + tr + ib;
    *reinterpret_cast<u32x4*>(drow)     = p0.v;
    *reinterpret_cast<u32x4*>(drow + 8) = p1.v;
}

// ---------------------------------------------------------------------------
// Barrier-light GEMM: C[16384 x 256] = A[M x K] * B^T[N x K].
// Block: 256 m-rows x 64 n-cols (MT m-tiles; MT=1 in all launches so the
// grid is large enough to FILL 4 blocks/CU). B panel (64 x 256K half =
// 32 KB LDS, chunk-swizzled phys = c ^ (row&7)) staged per block/kh.
// Wave: 64 m-rows (4 sets of 16) x 64 cols; acc[4][4] (64 regs).
// OPERAND-SWAPPED MFMA: mfma(Bfrag, Afrag) = D^T: lane owns m-row l16 with
// 4 CONSECUTIVE n-cols per acc reg set.
// Epilogue: per 16-row set, TWO column-half passes (nf in {0,1} then {2,3})
// through per-wave fs[16 rows][8 slots x 16B] (2 KB/wave, 8 KB total):
//   write: slot=(nf&1)*4+quad, phys=slot^(l16&7), ds_write_b128 of raw acc
//   read:  lane (rl=lane>>2, ch2=lane&3) reads logical slots 2ch2,2ch2+1
//          (phys = (2ch2)^(rl&7), ^1) -> 8 consecutive cols h*32+ch2*8
//   store: 16-B bf16 -> 64-B row segments, 64-B aligned = FULL sectors
//          (r4 lesson: 32-B segments triggered write-allocate RMW).
// Same DS-op count as the 16-slot version; half the LDS.
// bias/gamma: <=8 named f32x4 regs loaded once (r5 lesson: no arrays).
// LDS: Bs 32KB + fs 8KB = 40KB -> 4 blocks/CU (r6 was 48KB -> 3; occupancy
// was the limiter: 28% occ, all pipes <25% busy). __launch_bounds__(256,4).
// mode 1: in_proj  z=(k3*4+e): k3<2 -> out0 interleaved *gamma +bias ; k3==2 -> out1 plain +bias
// mode 2: mid      z=e: + (mid_b0-mid_b1) + aux(o) -> out0
// mode 3: ff1      z=e: +bias, exact gelu -> out0
// mode 4: ff2      z=e: +bias + aux(residual) -> out0
// ---------------------------------------------------------------------------
__global__ __launch_bounds__(256, 4) void gemm_k(
    const u16* __restrict__ A0, const u16* __restrict__ B0,
    const float* __restrict__ biasf, const u16* __restrict__ aux,
    const float* __restrict__ gamlogf, u16* __restrict__ out0,
    u16* __restrict__ out1, int K, int mode, int MT)
{
    __shared__ __align__(16) u16 Bs[64 * 256];      // 32 KB, [n][k-half], swizzled 16B chunks
    __shared__ __align__(16) float fs_all[4][512];  // 8 KB, per-wave [16 rows][8 slots x 4 f32]

    int tid  = threadIdx.x;
    int wave = tid >> 6, lane = tid & 63;
    int quad = lane >> 4, l16 = lane & 15;
    int n0 = blockIdx.y * 64;
    int z = blockIdx.z;
    int e, k3 = 0;
    const u16* A;
    const u16* Bm;
    if (mode == 1) { k3 = z >> 2; e = z & 3; A = A0; }
    else           { e = z; A = A0 + (size_t)e * BT_ * K; }
    Bm = B0 + (size_t)(mode == 1 ? z : e) * 256 * K;

    int srow = lane >> 5, schunk = lane & 31;   // staging: 2 rows x 32 chunks / instr
    int nhalf = K >> 8;                          // 1 (K=256) or 2 (K=512)

    float* fsw = fs_all[wave];
    int rl = lane >> 2, ch2 = lane & 3;

    // readback-side constants: pass h covers cols n0 + h*32 + ch2*8 .. +7
    // (mt/s-invariant) -> named vector registers only, loaded once.
    int cb0 = n0 + ch2 * 8;        // pass 0 base col
    int cb1 = cb0 + 32;            // pass 1 base col
    f32x4 b0l, b0h, b1l, b1h;
    f32x4 g0l = (f32x4){1.f,1.f,1.f,1.f}, g0h = g0l, g1l = g0l, g1h = g0l;
    if (mode == 1) {
        b0l = *reinterpret_cast<const f32x4*>(biasf + z * 256 + cb0);
        b0h = *reinterpret_cast<const f32x4*>(biasf + z * 256 + cb0 + 4);
        b1l = *reinterpret_cast<const f32x4*>(biasf + z * 256 + cb1);
        b1h = *reinterpret_cast<const f32x4*>(biasf + z * 256 + cb1 + 4);
        if (k3 < 2) {
            f32x4 t0 = *reinterpret_cast<const f32x4*>(gamlogf + 2048 + e * 256 + cb0);
            f32x4 t1 = *reinterpret_cast<const f32x4*>(gamlogf + 2048 + e * 256 + cb0 + 4);
            f32x4 t2 = *reinterpret_cast<const f32x4*>(gamlogf + 2048 + e * 256 + cb1);
            f32x4 t3 = *reinterpret_cast<const f32x4*>(gamlogf + 2048 + e * 256 + cb1 + 4);
#pragma unroll
            for (int r = 0; r < 4; r++) {
                g0l[r] = expf(t0[r]); g0h[r] = expf(t1[r]);
                g1l[r] = expf(t2[r]); g1h[r] = expf(t3[r]);
            }
        }
    } else if (mode == 2) {
        f32x4 a0 = *reinterpret_cast<const f32x4*>(biasf + e * 256 + cb0);
        f32x4 a1 = *reinterpret_cast<const f32x4*>(biasf + e * 256 + cb0 + 4);
        f32x4 a2 = *reinterpret_cast<const f32x4*>(biasf + e * 256 + cb1);
        f32x4 a3 = *reinterpret_cast<const f32x4*>(biasf + e * 256 + cb1 + 4);
        f32x4 c0 = *reinterpret_cast<const f32x4*>(biasf + 1024 + e * 256 + cb0);
        f32x4 c1 = *reinterpret_cast<const f32x4*>(biasf + 1024 + e * 256 + cb0 + 4);
        f32x4 c2 = *reinterpret_cast<const f32x4*>(biasf + 1024 + e * 256 + cb1);
        f32x4 c3 = *reinterpret_cast<const f32x4*>(biasf + 1024 + e * 256 + cb1 + 4);
        b0l = a0 - c0; b0h = a1 - c1; b1l = a2 - c2; b1h = a3 - c3;
    } else {
        b0l = *reinterpret_cast<const f32x4*>(biasf + e * 256 + cb0);
        b0h = *reinterpret_cast<const f32x4*>(biasf + e * 256 + cb0 + 4);
        b1l = *reinterpret_cast<const f32x4*>(biasf + e * 256 + cb1);
        b1h = *reinterpret_cast<const f32x4*>(biasf + e * 256 + cb1 + 4);
    }

    for (int mt = 0; mt < MT; mt++) {
        int m0 = (blockIdx.x * MT + mt) * 256;

        f32x4 acc[4][4];
#pragma unroll
        for (int i = 0; i < 4; i++)
#pragma unroll
            for (int j = 0; j < 4; j++) acc[i][j] = (f32x4){0.f, 0.f, 0.f, 0.f};

        for (int kh = 0; kh < nhalf; kh++) {
            if (nhalf > 1 || mt == 0) {          // (re)stage B panel half
                if (mt || kh) __syncthreads();   // readers of previous content done
#pragma unroll
                for (int i = 0; i < 8; i++) {
                    int row = wave * 16 + i * 2 + srow;
                    int c = schunk ^ (row & 7);
                    gload_lds16(Bm + (size_t)(n0 + row) * K + kh * 256 + c * 8,
                                &Bs[(wave * 16 + i * 2) * 256]);
                }
                __syncthreads();                 // drains staging DMA (vmcnt 0)
            }

            const u16* Ar0 = A + (size_t)(m0 + wave * 64 + l16) * K + kh * 256 + quad * 8;
            const u16* Ar1 = Ar0 + (size_t)16 * K;
            const u16* Ar2 = Ar0 + (size_t)32 * K;
            const u16* Ar3 = Ar0 + (size_t)48 * K;

            bf16x8 ac0, ac1, ac2, ac3, an0, an1, an2, an3;
            { union { u32x4 v; bf16x8 b; } u;
              u.v = *reinterpret_cast<const u32x4*>(Ar0); ac0 = u.b;
              u.v = *reinterpret_cast<const u32x4*>(Ar1); ac1 = u.b;
              u.v = *reinterpret_cast<const u32x4*>(Ar2); ac2 = u.b;
              u.v = *reinterpret_cast<const u32x4*>(Ar3); ac3 = u.b; }
#pragma unroll
            for (int kt = 0; kt < 8; kt++) {
                if (kt < 7) {
                    union { u32x4 v; bf16x8 b; } u;
                    u.v = *reinterpret_cast<const u32x4*>(Ar0 + (kt + 1) * 32); an0 = u.b;
                    u.v = *reinterpret_cast<const u32x4*>(Ar1 + (kt + 1) * 32); an1 = u.b;
                    u.v = *reinterpret_cast<const u32x4*>(Ar2 + (kt + 1) * 32); an2 = u.b;
                    u.v = *reinterpret_cast<const u32x4*>(Ar3 + (kt + 1) * 32); an3 = u.b;
                }
#pragma unroll
                for (int nf = 0; nf < 4; nf++) {
                    int row = nf * 16 + l16;
                    int c = (kt * 4 + quad) ^ (row & 7);
                    union { u32x4 v; bf16x8 b; } u;
                    u.v = *reinterpret_cast<const u32x4*>(&Bs[row * 256 + c * 8]);
                    // swapped operands: D^T — lane = m-row, regs = 4 consecutive n-cols
                    acc[0][nf] = __builtin_amdgcn_mfma_f32_16x16x32_bf16(u.b, ac0, acc[0][nf], 0, 0, 0);
                    acc[1][nf] = __builtin_amdgcn_mfma_f32_16x16x32_bf16(u.b, ac1, acc[1][nf], 0, 0, 0);
                    acc[2][nf] = __builtin_amdgcn_mfma_f32_16x16x32_bf16(u.b, ac2, acc[2][nf], 0, 0, 0);
                    acc[3][nf] = __builtin_amdgcn_mfma_f32_16x16x32_bf16(u.b, ac3, acc[3][nf], 0, 0, 0);
                }
                ac0 = an0; ac1 = an1; ac2 = an2; ac3 = an3;
            }
        }

        // epilogue: per 16-row set s, two column-half passes through fs
#pragma unroll
        for (int s = 0; s < 4; s++) {
#pragma unroll
            for (int h = 0; h < 2; h++) {
#pragma unroll
                for (int j = 0; j < 2; j++) {
                    int nf = 2 * h + j;
                    int phys = ((j << 2) + quad) ^ (l16 & 7);
                    *reinterpret_cast<f32x4*>(fsw + l16 * 32 + phys * 4) = acc[s][nf];
                }
                int pa = (2 * ch2) ^ (rl & 7);
                f32x4 lo = *reinterpret_cast<const f32x4*>(fsw + rl * 32 + pa * 4);
                f32x4 hi = *reinterpret_cast<const f32x4*>(fsw + rl * 32 + (pa ^ 1) * 4);
                lo += h ? b1l : b0l;
                hi += h ? b1h : b0h;
                if (mode == 1) { lo *= h ? g1l : g0l; hi *= h ? g1h : g0h; }
                if (mode == 3) {
#pragma unroll
                    for (int r = 0; r < 4; r++) {
                        lo[r] = 0.5f * lo[r] * (1.0f + erff(lo[r] * 0.70710678118654752f));
                        hi[r] = 0.5f * hi[r] * (1.0f + erff(hi[r] * 0.70710678118654752f));
                    }
                }
                int grow = m0 + wave * 64 + s * 16 + rl;
                int colb = h ? cb1 : cb0;
                u16* dstp;
                if (mode == 1) {
                    if (k3 < 2) dstp = out0 + (((size_t)(e * BT_ + grow)) * 2 + k3) * 256 + colb;
                    else        dstp = out1 + ((size_t)e * BT_ + grow) * 256 + colb;
                } else {
                    dstp = out0 + ((size_t)e * BT_ + grow) * 256 + colb;
                }
                if (mode == 2 || mode == 4) {
                    const u16* ap = aux + ((size_t)e * BT_ + grow) * 256 + colb;
                    u32x4 av = *reinterpret_cast<const u32x4*>(ap);
                    lo[0] += b2f((u16)(av[0] & 0xffffu)); lo[1] += b2f((u16)(av[0] >> 16));
                    lo[2] += b2f((u16)(av[1] & 0xffffu)); lo[3] += b2f((u16)(av[1] >> 16));
                    hi[0] += b2f((u16)(av[2] & 0xffffu)); hi[1] += b2f((u16)(av[2] >> 16));
                    hi[2] += b2f((u16)(av[3] & 0xffffu)); hi[3] += b2f((u16)(av[3] >> 16));
                }
                u32x4 pv;
                pv[0] = (unsigned int)f2b(lo[0]) | ((unsigned int)f2b(lo[1]) << 16);
                pv[1] = (unsigned int)f2b(lo[2]) | ((unsigned int)f2b(lo[3]) << 16);
                pv[2] = (unsigned int)f2b(hi[0]) | ((unsigned int)f2b(hi[1]) << 16);
                pv[3] = (unsigned int)f2b(hi[2]) | ((unsigned int)f2b(hi[3]) << 16);
                *reinterpret_cast<u32x4*>(dstp) = pv;
            }
        }
    }
}

// ---------------------------------------------------------------------------
// LRU scan, 3 phases, 2 d-lanes per thread (u32 loads/stores).
// buf_u layout: ((e*BT + b*T + t)*2 + c)*256 + d  (c=0:re, 1:im)
// ---------------------------------------------------------------------------
__global__ __launch_bounds__(256) void scan_a(const u16* __restrict__ u,
    const float* __restrict__ plog, float2* __restrict__ carry)
{
    int l2 = blockIdx.x * 256 + threadIdx.x;      // < 8192
    int chunk = blockIdx.y;
    int dd = (l2 & 127) * 2, b = (l2 >> 7) & 15, e = l2 >> 11;
    float nu0 = expf(plog[e * 256 + dd]),        nu1 = expf(plog[e * 256 + dd + 1]);
    float th0 = expf(plog[1024 + e * 256 + dd]), th1 = expf(plog[1024 + e * 256 + dd + 1]);
    float m0 = expf(-nu0), m1 = expf(-nu1);
    float fr0 = m0 * cosf(th0), fi0 = m0 * sinf(th0);
    float fr1 = m1 * cosf(th1), fi1 = m1 * sinf(th1);
    size_t base = ((size_t)e * BT_ + b * TT) * 512 + (size_t)chunk * CLEN * 512 + dd;
    float hr0 = 0.f, hi0 = 0.f, hr1 = 0.f, hi1 = 0.f;
    for (int t = 0; t < CLEN; t++) {
        unsigned int wr = *reinterpret_cast<const unsigned int*>(u + base);
        unsigned int wi = *reinterpret_cast<const unsigned int*>(u + base + 256);
        float ur0 = b2f((u16)wr), ur1 = b2f((u16)(wr >> 16));
        float ui0 = b2f((u16)wi), ui1 = b2f((u16)(wi >> 16));
        float a0 = fr0 * hr0 - fi0 * hi0 + ur0;
        float b0 = fr0 * hi0 + fi0 * hr0 + ui0;
        float a1 = fr1 * hr1 - fi1 * hi1 + ur1;
        float b1 = fr1 * hi1 + fi1 * hr1 + ui1;
        hr0 = a0; hi0 = b0; hr1 = a1; hi1 = b1;
        base += 512;
    }
    size_t ci = (size_t)chunk * LANES + (size_t)e * 4096 + b * 256 + dd;
    *reinterpret_cast<float4*>(&carry[ci]) = make_float4(hr0, hi0, hr1, hi1);
}

__global__ __launch_bounds__(256) void scan_b(const float* __restrict__ plog,
                                              float2* __restrict__ carry)
{
    int l = blockIdx.x * 256 + threadIdx.x;
    int d = l & 255, e = l >> 12;
    float nu = expf(plog[e * 256 + d]);
    float th = expf(plog[1024 + e * 256 + d]);
    float magL = expf(-nu * (float)CLEN);
    float ang = th * (float)CLEN;
    float frL = magL * cosf(ang), fiL = magL * sinf(ang);
    float gr = 0.f, gi = 0.f;
    for (int j = 0; j < CHUNKS; j++) {
        float2 c = carry[(size_t)j * LANES + l];
        carry[(size_t)j * LANES + l] = make_float2(gr, gi);
        float gr2 = frL * gr - fiL * gi + c.x;
        float gi2 = frL * gi + fiL * gr + c.y;
        gr = gr2; gi = gi2;
    }
}

// scan_c also writes hidden (fp32, exact) on the last chunk.
__global__ __launch_bounds__(256) void scan_c(u16* __restrict__ u,
    const float* __restrict__ plog, const float2* __restrict__ carry,
    float* __restrict__ outh)
{
    int l2 = blockIdx.x * 256 + threadIdx.x;      // < 8192
    int chunk = blockIdx.y;
    int dd = (l2 & 127) * 2, b = (l2 >> 7) & 15, e = l2 >> 11;
    float nu0 = expf(plog[e * 256 + dd]),        nu1 = expf(plog[e * 256 + dd + 1]);
    float th0 = expf(plog[1024 + e * 256 + dd]), th1 = expf(plog[1024 + e * 256 + dd + 1]);
    float m0 = expf(-nu0), m1 = expf(-nu1);
    float fr0 = m0 * cosf(th0), fi0 = m0 * sinf(th0);
    float fr1 = m1 * cosf(th1), fi1 = m1 * sinf(th1);
    size_t base = ((size_t)e * BT_ + b * TT) * 512 + (size_t)chunk * CLEN * 512 + dd;
    size_t ci = (size_t)chunk * LANES + (size_t)e * 4096 + b * 256 + dd;
    float4 c0 = *reinterpret_cast<const float4*>(&carry[ci]);
    float hr0 = c0.x, hi0 = c0.y, hr1 = c0.z, hi1 = c0.w;
    for (int t = 0; t < CLEN; t++) {
        unsigned int wr = *reinterpret_cast<const unsigned int*>(u + base);
        unsigned int wi = *reinterpret_cast<const unsigned int*>(u + base + 256);
        float ur0 = b2f((u16)wr), ur1 = b2f((u16)(wr >> 16));
        float ui0 = b2f((u16)wi), ui1 = b2f((u16)(wi >> 16));
        float a0 = fr0 * hr0 - fi0 * hi0 + ur0;
        float b0 = fr0 * hi0 + fi0 * hr0 + ui0;
        float a1 = fr1 * hr1 - fi1 * hi1 + ur1;
        float b1 = fr1 * hi1 + fi1 * hr1 + ui1;
        hr0 = a0; hi0 = b0; hr1 = a1; hi1 = b1;
        *reinterpret_cast<unsigned int*>(u + base) =
            (unsigned int)f2b(hr0) | ((unsigned int)f2b(hr1) << 16);
        *reinterpret_cast<unsigned int*>(u + base + 256) =
            (unsigned int)f2b(hi0) | ((unsigned int)f2b(hi1) << 16);
        base += 512;
    }
    if (chunk == CHUNKS - 1) {
        float* oh = outh + (size_t)4 * BT_ * 256;
        *reinterpret_cast<float2*>(&oh[b * 2048 + e * 256 + dd])        = make_float2(hr0, hr1);
        *reinterpret_cast<float2*>(&oh[b * 2048 + 1024 + e * 256 + dd]) = make_float2(hi0, hi1);
    }
}

// LayerNorm across (e,d) per row r=(b,t); h2 plain (E, BT, D) bf16; fp32 out
__global__ __launch_bounds__(256) void ln_k(const u16* __restrict__ h2,
    const float* __restrict__ lnw, const float* __restrict__ lnb,
    float* __restrict__ out)
{
    int r = blockIdx.x;
    int d = threadIdx.x;
    float v[4]; float s1 = 0.f, s2 = 0.f;
#pragma unroll
    for (int e = 0; e < 4; e++) {
        float x = b2f(h2[((size_t)e * BT_ + r) * 256 + d]);
        v[e] = x; s1 += x; s2 += x * x;
    }
#pragma unroll
    for (int off = 32; off; off >>= 1) {
        s1 += __shfl_down(s1, off, 64);
        s2 += __shfl_down(s2, off, 64);
    }
    __shared__ float sm[8];
    int wave = threadIdx.x >> 6, lane = threadIdx.x & 63;
    if (lane == 0) { sm[wave] = s1; sm[4 + wave] = s2; }
    __syncthreads();
    float S1 = sm[0] + sm[1] + sm[2] + sm[3];
    float S2 = sm[4] + sm[5] + sm[6] + sm[7];
    float mean = S1 * (1.0f / 1024.0f);
    float var = S2 * (1.0f / 1024.0f) - mean * mean;
    float rstd = rsqrtf(var + 1e-5f);
#pragma unroll
    for (int e = 0; e < 4; e++) {
        float o = (v[e] - mean) * rstd * lnw[e * 256 + d] + lnb[e * 256 + d];
        out[((size_t)e * BT_ + r) * 256 + d] = o;
    }
}

extern "C" void kernel_launch(void* const* d_in, const int* in_sizes, int n_in,
                              void* d_out, int out_size, void* d_ws, size_t ws_size,
                              hipStream_t stream)
{
    const float* x    = (const float*)d_in[0];
    const float* ipw  = (const float*)d_in[1];
    const float* ipb  = (const float*)d_in[2];
    const float* plog = (const float*)d_in[3];
    const float* mw   = (const float*)d_in[4];
    const float* mb   = (const float*)d_in[5];
    const float* fw1  = (const float*)d_in[6];
    const float* fb1  = (const float*)d_in[7];
    const float* fw2  = (const float*)d_in[8];
    const float* fb2  = (const float*)d_in[9];
    const float* lnw  = (const float*)d_in[10];
    const float* lnb  = (const float*)d_in[11];
    float* out = (float*)d_out;

    // Workspace (u16 elem offsets; ~99.5 MiB):
    //   buf_u    [0,          33,554,432)  scan buffer (E,BT,2,D) bf16, later h2
    //   buf_out  [33,554,432, 50,331,648)  mid output bf16; ALIASED early by:
    //              xc (bf16 x, 4,194,304) at 33,554,432   [dead after in_proj]
    //              carry (float2, 4 MiB)  at 37,748,736   [dead after scan_c]
    //   buf_mw_t [50,331,648, 50,855,936)  [e][o][c*256+d] stacked, sign-folded
    //   c_ipw_t  [50,855,936, 51,642,368)  [z][o][i]
    //   c_fw1_t  [51,642,368, 51,904,512)  [e][o][d]
    //   c_fw2_t  [51,904,512, 52,166,656)  [e][o][d]
    // d_out bytes [0, 33.5 MB) double as bf16 scratch for `o` then `h1`.
    u16* W = (u16*)d_ws;
    u16* buf_u    = W;
    u16* buf_out  = W + (size_t)33554432;
    u16* xc       = W + (size_t)33554432;
    float2* carry = (float2*)(W + (size_t)37748736);
    u16* buf_mw_t = W + (size_t)50331648;
    u16* c_ipw_t  = W + (size_t)50855936;
    u16* c_fw1_t  = W + (size_t)51642368;
    u16* c_fw2_t  = W + (size_t)51904512;
    u16* scratch  = (u16*)d_out;

    conv_k<<<2048, 256, 0, stream>>>(x, xc);
    prep_w<<<448, 256, 0, stream>>>(ipw, mw, fw1, fw2, c_ipw_t, buf_mw_t, c_fw1_t, c_fw2_t);
    // in_proj: u0,u1 (gamma-scaled, interleaved) -> buf_u ; o -> d_out scratch
    gemm_k<<<dim3(64, 4, 12), 256, 0, stream>>>(xc, c_ipw_t, ipb, nullptr, plog, buf_u, scratch, 256, 1, 1);
    // LRU scan (chunked, 3 phases), in-place in buf_u (xc dead now); hidden fused into scan_c
    scan_a<<<dim3(32, CHUNKS), 256, 0, stream>>>(buf_u, plog, carry);
    scan_b<<<64, 256, 0, stream>>>(plog, carry);
    scan_c<<<dim3(32, CHUNKS), 256, 0, stream>>>(buf_u, plog, carry, out);
    // mid (K=512 fused r/i) + o -> buf_out   (carry dead now)
    gemm_k<<<dim3(64, 4, 4), 256, 0, stream>>>(buf_u, buf_mw_t, mb, scratch, nullptr, buf_out, nullptr, 512, 2, 1);
    // ff1 + gelu -> d_out scratch (h1; `o` dead)
    gemm_k<<<dim3(64, 4, 4), 256, 0, stream>>>(buf_out, c_fw1_t, fb1, nullptr, nullptr, scratch, nullptr, 256, 3, 1);
    // ff2 + residual -> buf_u (h2 plain; scan data dead)
    gemm_k<<<dim3(64, 4, 4), 256, 0, stream>>>(scratch, c_fw2_t, fb2, buf_out, nullptr, buf_u, nullptr, 256, 4, 1);
    // layernorm across (e,d) -> d_out fp32 (overwrites scratch region last)
    ln_k<<<16384, 256, 0, stream>>>(buf_u, lnw, lnb, out);
}

// Round 9
// 445.434 us; speedup vs baseline: 1.0207x; 1.0207x over previous
//
#include <hip/hip_runtime.h>
#include <stdint.h>

#define BT_ 16384   // B*T
#define TT  1024
#define CHUNKS 32
#define CLEN   32
#define LANES  16384  // E*B*D

typedef __bf16 bf16x8 __attribute__((ext_vector_type(8)));
typedef float  f32x4  __attribute__((ext_vector_type(4)));
typedef unsigned int u32x4 __attribute__((ext_vector_type(4)));
typedef unsigned int u32x2 __attribute__((ext_vector_type(2)));
typedef unsigned short u16;

__device__ __forceinline__ float b2f(u16 s){
    union { float f; unsigned int u; } c; c.u = ((unsigned int)s) << 16; return c.f;
}
__device__ __forceinline__ u16 f2b(float f){
    union { float f; unsigned int u; } c; c.f = f;
    unsigned int u = c.u;
    return (u16)((u + 0x7fffu + ((u >> 16) & 1u)) >> 16);
}

// async global->LDS, 16 B per lane; LDS dest is wave-uniform base + lane*16
__device__ __forceinline__ void gload_lds16(const u16* g, u16* lds){
    __builtin_amdgcn_global_load_lds(
        (const __attribute__((address_space(1))) void*)g,
        (__attribute__((address_space(3))) void*)lds, 16, 0, 0);
}

// ---------------------------------------------------------------------------
// x: fp32 -> bf16 (A operand of in_proj), 8 elems/thread, 16B stores
// ---------------------------------------------------------------------------
__global__ __launch_bounds__(256) void conv_k(const float* __restrict__ x, u16* __restrict__ xc)
{
    long i = ((long)blockIdx.x * 256 + threadIdx.x) * 8;   // < 4,194,304
    float4 v0 = *reinterpret_cast<const float4*>(x + i);
    float4 v1 = *reinterpret_cast<const float4*>(x + i + 4);
    union { u16 s[8]; u32x4 v; } p;
    p.s[0] = f2b(v0.x); p.s[1] = f2b(v0.y); p.s[2] = f2b(v0.z); p.s[3] = f2b(v0.w);
    p.s[4] = f2b(v1.x); p.s[5] = f2b(v1.y); p.s[6] = f2b(v1.z); p.s[7] = f2b(v1.w);
    *reinterpret_cast<u32x4*>(xc + i) = p.v;
}

// ---------------------------------------------------------------------------
// Weight prep: fp32 -> bf16, TRANSPOSED to [n][k].
// 28 source matrices of 256x256 ([i][o], o contiguous):
//   w in [0,12)  : in_proj (z=k3*4+e)      -> c_ipw_t + w*65536          , ostride 256
//   w in [12,20) : mid (c=(w-12)>>2,e=&3)  -> buf_mw_t + e*131072 + c*256, ostride 512, sign -1 for c=1
//   w in [20,24) : ff_w1 (e)               -> c_fw1_t + e*65536          , ostride 256
//   w in [24,28) : ff_w2 (e)               -> c_fw2_t + e*65536          , ostride 256
// ---------------------------------------------------------------------------
__global__ __launch_bounds__(256) void prep_w(
    const float* __restrict__ ipw, const float* __restrict__ mw,
    const float* __restrict__ fw1, const float* __restrict__ fw2,
    u16* __restrict__ d_ipw, u16* __restrict__ d_mw,
    u16* __restrict__ d_fw1, u16* __restrict__ d_fw2)
{
    __shared__ u16 tile[64][72];
    int blk = blockIdx.x;            // < 448
    int w = blk >> 4, t = blk & 15;
    int tr = (t >> 2) * 64;          // i origin
    int tc = (t & 3) * 64;           // o origin
    const float* src; u16* dst; int ostride; float sign = 1.f;
    if (w < 12)      { src = ipw + (size_t)w * 65536; dst = d_ipw + (size_t)w * 65536; ostride = 256; }
    else if (w < 20) { int u = w - 12, c = u >> 2, e = u & 3;
                       src = mw + (size_t)u * 65536;
                       dst = d_mw + (size_t)e * 131072 + c * 256; ostride = 512;
                       if (c) sign = -1.f; }
    else if (w < 24) { int e = w - 20; src = fw1 + (size_t)e * 65536; dst = d_fw1 + (size_t)e * 65536; ostride = 256; }
    else             { int e = w - 24; src = fw2 + (size_t)e * 65536; dst = d_fw2 + (size_t)e * 65536; ostride = 256; }

    int q = threadIdx.x;
    int r = q >> 2, cb = (q & 3) * 16;
#pragma unroll
    for (int j = 0; j < 4; j++) {
        int col = cb + j * 4;
        const float4 v = *reinterpret_cast<const float4*>(src + (size_t)(tr + r) * 256 + tc + col);
        tile[r][col + 0] = f2b(v.x * sign);
        tile[r][col + 1] = f2b(v.y * sign);
        tile[r][col + 2] = f2b(v.z * sign);
        tile[r][col + 3] = f2b(v.w * sign);
    }
    __syncthreads();
    int ol = q >> 2, ib = (q & 3) * 16;
    union { u16 s[8]; u32x4 v; } p0, p1;
#pragma unroll
    for (int k = 0; k < 8; k++) { p0.s[k] = tile[ib + k][ol]; p1.s[k] = tile[ib + 8 + k][ol]; }
    u16* drow = dst + (size_t)(tc + ol) * ostride + tr + ib;
    *reinterpret_cast<u32x4*>(drow)     = p0.v;
    *reinterpret_cast<u32x4*>(drow + 8) = p1.v;
}

// ---------------------------------------------------------------------------
// Barrier-light GEMM: C[16384 x 256] = A[M x K] * B^T[N x K].
// Block: 256 m-rows x 64 n-cols (MT=1 in all launches; grid fills 4 bl/CU).
// B panel (64 x 256K half = 32 KB LDS, chunk-swizzled phys = c ^ (row&7)).
// Wave: 64 m-rows (4 sets of 16) x 64 cols; acc[4][4] (64 regs).
// OPERAND-SWAPPED MFMA: mfma(Bfrag, Afrag) = D^T: lane owns m-row l16 with
// 4 CONSECUTIVE n-cols per acc reg set.
// Epilogue — HW rule (r3/r4/r6/r7): global stores must cover FULL 128-B
// lines within ONE instruction (64-B/32-B segments trigger write-allocate
// RMW). Per 16-row set, TWO 8-row passes through per-wave fs[8][64] f32
// (2 KB/wave):
//   write: HALF-WAVE (lanes l16>>3==p) stage 4 acc f32x4 each,
//          slot phys=(nf*4+quad)^(l16&7)
//   read:  all 64 lanes (row=lane>>3, ch=lane&7), logical slots 2ch,2ch+1
//   store: 16 B/lane, 8 lanes/row -> full 128-B lines. Aux loads 16 B.
// r8 LESSON (correctness): with a CONDITIONAL write, a non-writing thread
// has no aliasing write between the p=0 and p=1 reads at the SAME address,
// so LLVM's per-thread model may CSE the reads (cross-lane LDS writes are
// invisible without a sync point) -> stale rows, absmax 7.0. Fix: zero-cost
// compiler fences asm volatile("" ::: "memory") after write-block and after
// reads. No instruction emitted (r5's lgkmcnt(0)+clobber serialized because
// scratch ARRAYS were live; here all epilogue state is SSA regs). HW DS pipe
// is in-order per wave, so compiler-order == execution-order suffices.
// LDS: Bs 32KB + fs 8KB = 40KB -> 4 blocks/CU. __launch_bounds__(256,4).
// mode 1: in_proj  z=(k3*4+e): k3<2 -> out0 interleaved *gamma +bias ; k3==2 -> out1 plain +bias
// mode 2: mid      z=e: + (mid_b0-mid_b1) + aux(o) -> out0
// mode 3: ff1      z=e: +bias, exact gelu -> out0
// mode 4: ff2      z=e: +bias + aux(residual) -> out0
// ---------------------------------------------------------------------------
__global__ __launch_bounds__(256, 4) void gemm_k(
    const u16* __restrict__ A0, const u16* __restrict__ B0,
    const float* __restrict__ biasf, const u16* __restrict__ aux,
    const float* __restrict__ gamlogf, u16* __restrict__ out0,
    u16* __restrict__ out1, int K, int mode, int MT)
{
    __shared__ __align__(16) u16 Bs[64 * 256];      // 32 KB, [n][k-half], swizzled 16B chunks
    __shared__ __align__(16) float fs_all[4][512];  // 8 KB, per-wave [8 rows][64 cols] f32

    int tid  = threadIdx.x;
    int wave = tid >> 6, lane = tid & 63;
    int quad = lane >> 4, l16 = lane & 15;
    int n0 = blockIdx.y * 64;
    int z = blockIdx.z;
    int e, k3 = 0;
    const u16* A;
    const u16* Bm;
    if (mode == 1) { k3 = z >> 2; e = z & 3; A = A0; }
    else           { e = z; A = A0 + (size_t)e * BT_ * K; }
    Bm = B0 + (size_t)(mode == 1 ? z : e) * 256 * K;

    int srow = lane >> 5, schunk = lane & 31;   // staging: 2 rows x 32 chunks / instr
    int nhalf = K >> 8;                          // 1 (K=256) or 2 (K=512)

    float* fsw = fs_all[wave];
    int rl8 = lane >> 3, ch = lane & 7;

    // readback constants: lane covers cols colb..colb+7 for ALL passes/sets
    // -> 4 named f32x4 registers, loaded once (r5 lesson: no arrays)
    int colb = n0 + ch * 8;
    f32x4 bias_lo, bias_hi;
    f32x4 gam_lo = (f32x4){1.f, 1.f, 1.f, 1.f}, gam_hi = gam_lo;
    if (mode == 1) {
        bias_lo = *reinterpret_cast<const f32x4*>(biasf + z * 256 + colb);
        bias_hi = *reinterpret_cast<const f32x4*>(biasf + z * 256 + colb + 4);
        if (k3 < 2) {
            f32x4 gl = *reinterpret_cast<const f32x4*>(gamlogf + 2048 + e * 256 + colb);
            f32x4 gh = *reinterpret_cast<const f32x4*>(gamlogf + 2048 + e * 256 + colb + 4);
#pragma unroll
            for (int r = 0; r < 4; r++) { gam_lo[r] = expf(gl[r]); gam_hi[r] = expf(gh[r]); }
        }
    } else if (mode == 2) {
        f32x4 a0 = *reinterpret_cast<const f32x4*>(biasf + e * 256 + colb);
        f32x4 a1 = *reinterpret_cast<const f32x4*>(biasf + e * 256 + colb + 4);
        f32x4 c0 = *reinterpret_cast<const f32x4*>(biasf + 1024 + e * 256 + colb);
        f32x4 c1 = *reinterpret_cast<const f32x4*>(biasf + 1024 + e * 256 + colb + 4);
        bias_lo = a0 - c0; bias_hi = a1 - c1;
    } else {
        bias_lo = *reinterpret_cast<const f32x4*>(biasf + e * 256 + colb);
        bias_hi = *reinterpret_cast<const f32x4*>(biasf + e * 256 + colb + 4);
    }

    for (int mt = 0; mt < MT; mt++) {
        int m0 = (blockIdx.x * MT + mt) * 256;

        f32x4 acc[4][4];
#pragma unroll
        for (int i = 0; i < 4; i++)
#pragma unroll
            for (int j = 0; j < 4; j++) acc[i][j] = (f32x4){0.f, 0.f, 0.f, 0.f};

        for (int kh = 0; kh < nhalf; kh++) {
            if (nhalf > 1 || mt == 0) {          // (re)stage B panel half
                if (mt || kh) __syncthreads();   // readers of previous content done
#pragma unroll
                for (int i = 0; i < 8; i++) {
                    int row = wave * 16 + i * 2 + srow;
                    int c = schunk ^ (row & 7);
                    gload_lds16(Bm + (size_t)(n0 + row) * K + kh * 256 + c * 8,
                                &Bs[(wave * 16 + i * 2) * 256]);
                }
                __syncthreads();                 // drains staging DMA (vmcnt 0)
            }

            const u16* Ar0 = A + (size_t)(m0 + wave * 64 + l16) * K + kh * 256 + quad * 8;
            const u16* Ar1 = Ar0 + (size_t)16 * K;
            const u16* Ar2 = Ar0 + (size_t)32 * K;
            const u16* Ar3 = Ar0 + (size_t)48 * K;

            bf16x8 ac0, ac1, ac2, ac3, an0, an1, an2, an3;
            { union { u32x4 v; bf16x8 b; } u;
              u.v = *reinterpret_cast<const u32x4*>(Ar0); ac0 = u.b;
              u.v = *reinterpret_cast<const u32x4*>(Ar1); ac1 = u.b;
              u.v = *reinterpret_cast<const u32x4*>(Ar2); ac2 = u.b;
              u.v = *reinterpret_cast<const u32x4*>(Ar3); ac3 = u.b; }
#pragma unroll
            for (int kt = 0; kt < 8; kt++) {
                if (kt < 7) {
                    union { u32x4 v; bf16x8 b; } u;
                    u.v = *reinterpret_cast<const u32x4*>(Ar0 + (kt + 1) * 32); an0 = u.b;
                    u.v = *reinterpret_cast<const u32x4*>(Ar1 + (kt + 1) * 32); an1 = u.b;
                    u.v = *reinterpret_cast<const u32x4*>(Ar2 + (kt + 1) * 32); an2 = u.b;
                    u.v = *reinterpret_cast<const u32x4*>(Ar3 + (kt + 1) * 32); an3 = u.b;
                }
#pragma unroll
                for (int nf = 0; nf < 4; nf++) {
                    int row = nf * 16 + l16;
                    int c = (kt * 4 + quad) ^ (row & 7);
                    union { u32x4 v; bf16x8 b; } u;
                    u.v = *reinterpret_cast<const u32x4*>(&Bs[row * 256 + c * 8]);
                    // swapped operands: D^T — lane = m-row, regs = 4 consecutive n-cols
                    acc[0][nf] = __builtin_amdgcn_mfma_f32_16x16x32_bf16(u.b, ac0, acc[0][nf], 0, 0, 0);
                    acc[1][nf] = __builtin_amdgcn_mfma_f32_16x16x32_bf16(u.b, ac1, acc[1][nf], 0, 0, 0);
                    acc[2][nf] = __builtin_amdgcn_mfma_f32_16x16x32_bf16(u.b, ac2, acc[2][nf], 0, 0, 0);
                    acc[3][nf] = __builtin_amdgcn_mfma_f32_16x16x32_bf16(u.b, ac3, acc[3][nf], 0, 0, 0);
                }
                ac0 = an0; ac1 = an1; ac2 = an2; ac3 = an3;
            }
        }

        // epilogue: per 16-row set s, two 8-row passes through fs[8][64]
#pragma unroll
        for (int s = 0; s < 4; s++) {
#pragma unroll
            for (int p = 0; p < 2; p++) {
                if ((l16 >> 3) == p) {
#pragma unroll
                    for (int nf = 0; nf < 4; nf++) {
                        int phys = (nf * 4 + quad) ^ (l16 & 7);
                        *reinterpret_cast<f32x4*>(fsw + (l16 & 7) * 64 + phys * 4) = acc[s][nf];
                    }
                }
                // compiler fence: forbid CSE/reorder of the cross-lane LDS
                // exchange (r8 failure); emits no instruction, HW DS pipe is
                // in-order per wave.
                asm volatile("" ::: "memory");
                int pa = (2 * ch) ^ rl8;
                f32x4 lo = *reinterpret_cast<const f32x4*>(fsw + rl8 * 64 + pa * 4);
                f32x4 hi = *reinterpret_cast<const f32x4*>(fsw + rl8 * 64 + (pa ^ 1) * 4);
                asm volatile("" ::: "memory");
                lo += bias_lo; hi += bias_hi;
                if (mode == 1) { lo *= gam_lo; hi *= gam_hi; }
                if (mode == 3) {
#pragma unroll
                    for (int r = 0; r < 4; r++) {
                        lo[r] = 0.5f * lo[r] * (1.0f + erff(lo[r] * 0.70710678118654752f));
                        hi[r] = 0.5f * hi[r] * (1.0f + erff(hi[r] * 0.70710678118654752f));
                    }
                }
                int grow = m0 + wave * 64 + s * 16 + p * 8 + rl8;
                u16* dstp;
                if (mode == 1) {
                    if (k3 < 2) dstp = out0 + (((size_t)(e * BT_ + grow)) * 2 + k3) * 256 + colb;
                    else        dstp = out1 + ((size_t)e * BT_ + grow) * 256 + colb;
                } else {
                    dstp = out0 + ((size_t)e * BT_ + grow) * 256 + colb;
                }
                if (mode == 2 || mode == 4) {
                    const u16* ap = aux + ((size_t)e * BT_ + grow) * 256 + colb;
                    u32x4 av = *reinterpret_cast<const u32x4*>(ap);
                    lo[0] += b2f((u16)(av[0] & 0xffffu)); lo[1] += b2f((u16)(av[0] >> 16));
                    lo[2] += b2f((u16)(av[1] & 0xffffu)); lo[3] += b2f((u16)(av[1] >> 16));
                    hi[0] += b2f((u16)(av[2] & 0xffffu)); hi[1] += b2f((u16)(av[2] >> 16));
                    hi[2] += b2f((u16)(av[3] & 0xffffu)); hi[3] += b2f((u16)(av[3] >> 16));
                }
                u32x4 pv;
                pv[0] = (unsigned int)f2b(lo[0]) | ((unsigned int)f2b(lo[1]) << 16);
                pv[1] = (unsigned int)f2b(lo[2]) | ((unsigned int)f2b(lo[3]) << 16);
                pv[2] = (unsigned int)f2b(hi[0]) | ((unsigned int)f2b(hi[1]) << 16);
                pv[3] = (unsigned int)f2b(hi[2]) | ((unsigned int)f2b(hi[3]) << 16);
                *reinterpret_cast<u32x4*>(dstp) = pv;
            }
        }
    }
}

// ---------------------------------------------------------------------------
// LRU scan, 3 phases, 2 d-lanes per thread (u32 loads/stores).
// buf_u layout: ((e*BT + b*T + t)*2 + c)*256 + d  (c=0:re, 1:im)
// ---------------------------------------------------------------------------
__global__ __launch_bounds__(256) void scan_a(const u16* __restrict__ u,
    const float* __restrict__ plog, float2* __restrict__ carry)
{
    int l2 = blockIdx.x * 256 + threadIdx.x;      // < 8192
    int chunk = blockIdx.y;
    int dd = (l2 & 127) * 2, b = (l2 >> 7) & 15, e = l2 >> 11;
    float nu0 = expf(plog[e * 256 + dd]),        nu1 = expf(plog[e * 256 + dd + 1]);
    float th0 = expf(plog[1024 + e * 256 + dd]), th1 = expf(plog[1024 + e * 256 + dd + 1]);
    float m0 = expf(-nu0), m1 = expf(-nu1);
    float fr0 = m0 * cosf(th0), fi0 = m0 * sinf(th0);
    float fr1 = m1 * cosf(th1), fi1 = m1 * sinf(th1);
    size_t base = ((size_t)e * BT_ + b * TT) * 512 + (size_t)chunk * CLEN * 512 + dd;
    float hr0 = 0.f, hi0 = 0.f, hr1 = 0.f, hi1 = 0.f;
    for (int t = 0; t < CLEN; t++) {
        unsigned int wr = *reinterpret_cast<const unsigned int*>(u + base);
        unsigned int wi = *reinterpret_cast<const unsigned int*>(u + base + 256);
        float ur0 = b2f((u16)wr), ur1 = b2f((u16)(wr >> 16));
        float ui0 = b2f((u16)wi), ui1 = b2f((u16)(wi >> 16));
        float a0 = fr0 * hr0 - fi0 * hi0 + ur0;
        float b0 = fr0 * hi0 + fi0 * hr0 + ui0;
        float a1 = fr1 * hr1 - fi1 * hi1 + ur1;
        float b1 = fr1 * hi1 + fi1 * hr1 + ui1;
        hr0 = a0; hi0 = b0; hr1 = a1; hi1 = b1;
        base += 512;
    }
    size_t ci = (size_t)chunk * LANES + (size_t)e * 4096 + b * 256 + dd;
    *reinterpret_cast<float4*>(&carry[ci]) = make_float4(hr0, hi0, hr1, hi1);
}

__global__ __launch_bounds__(256) void scan_b(const float* __restrict__ plog,
                                              float2* __restrict__ carry)
{
    int l = blockIdx.x * 256 + threadIdx.x;
    int d = l & 255, e = l >> 12;
    float nu = expf(plog[e * 256 + d]);
    float th = expf(plog[1024 + e * 256 + d]);
    float magL = expf(-nu * (float)CLEN);
    float ang = th * (float)CLEN;
    float frL = magL * cosf(ang), fiL = magL * sinf(ang);
    float gr = 0.f, gi = 0.f;
    for (int j = 0; j < CHUNKS; j++) {
        float2 c = carry[(size_t)j * LANES + l];
        carry[(size_t)j * LANES + l] = make_float2(gr, gi);
        float gr2 = frL * gr - fiL * gi + c.x;
        float gi2 = frL * gi + fiL * gr + c.y;
        gr = gr2; gi = gi2;
    }
}

// scan_c also writes hidden (fp32, exact) on the last chunk.
__global__ __launch_bounds__(256) void scan_c(u16* __restrict__ u,
    const float* __restrict__ plog, const float2* __restrict__ carry,
    float* __restrict__ outh)
{
    int l2 = blockIdx.x * 256 + threadIdx.x;      // < 8192
    int chunk = blockIdx.y;
    int dd = (l2 & 127) * 2, b = (l2 >> 7) & 15, e = l2 >> 11;
    float nu0 = expf(plog[e * 256 + dd]),        nu1 = expf(plog[e * 256 + dd + 1]);
    float th0 = expf(plog[1024 + e * 256 + dd]), th1 = expf(plog[1024 + e * 256 + dd + 1]);
    float m0 = expf(-nu0), m1 = expf(-nu1);
    float fr0 = m0 * cosf(th0), fi0 = m0 * sinf(th0);
    float fr1 = m1 * cosf(th1), fi1 = m1 * sinf(th1);
    size_t base = ((size_t)e * BT_ + b * TT) * 512 + (size_t)chunk * CLEN * 512 + dd;
    size_t ci = (size_t)chunk * LANES + (size_t)e * 4096 + b * 256 + dd;
    float4 c0 = *reinterpret_cast<const float4*>(&carry[ci]);
    float hr0 = c0.x, hi0 = c0.y, hr1 = c0.z, hi1 = c0.w;
    for (int t = 0; t < CLEN; t++) {
        unsigned int wr = *reinterpret_cast<const unsigned int*>(u + base);
        unsigned int wi = *reinterpret_cast<const unsigned int*>(u + base + 256);
        float ur0 = b2f((u16)wr), ur1 = b2f((u16)(wr >> 16));
        float ui0 = b2f((u16)wi), ui1 = b2f((u16)(wi >> 16));
        float a0 = fr0 * hr0 - fi0 * hi0 + ur0;
        float b0 = fr0 * hi0 + fi0 * hr0 + ui0;
        float a1 = fr1 * hr1 - fi1 * hi1 + ur1;
        float b1 = fr1 * hi1 + fi1 * hr1 + ui1;
        hr0 = a0; hi0 = b0; hr1 = a1; hi1 = b1;
        *reinterpret_cast<unsigned int*>(u + base) =
            (unsigned int)f2b(hr0) | ((unsigned int)f2b(hr1) << 16);
        *reinterpret_cast<unsigned int*>(u + base + 256) =
            (unsigned int)f2b(hi0) | ((unsigned int)f2b(hi1) << 16);
        base += 512;
    }
    if (chunk == CHUNKS - 1) {
        float* oh = outh + (size_t)4 * BT_ * 256;
        *reinterpret_cast<float2*>(&oh[b * 2048 + e * 256 + dd])        = make_float2(hr0, hr1);
        *reinterpret_cast<float2*>(&oh[b * 2048 + 1024 + e * 256 + dd]) = make_float2(hi0, hi1);
    }
}

// LayerNorm across (e,d) per row r=(b,t); h2 plain (E, BT, D) bf16; fp32 out
__global__ __launch_bounds__(256) void ln_k(const u16* __restrict__ h2,
    const float* __restrict__ lnw, const float* __restrict__ lnb,
    float* __restrict__ out)
{
    int r = blockIdx.x;
    int d = threadIdx.x;
    float v[4]; float s1 = 0.f, s2 = 0.f;
#pragma unroll
    for (int e = 0; e < 4; e++) {
        float x = b2f(h2[((size_t)e * BT_ + r) * 256 + d]);
        v[e] = x; s1 += x; s2 += x * x;
    }
#pragma unroll
    for (int off = 32; off; off >>= 1) {
        s1 += __shfl_down(s1, off, 64);
        s2 += __shfl_down(s2, off, 64);
    }
    __shared__ float sm[8];
    int wave = threadIdx.x >> 6, lane = threadIdx.x & 63;
    if (lane == 0) { sm[wave] = s1; sm[4 + wave] = s2; }
    __syncthreads();
    float S1 = sm[0] + sm[1] + sm[2] + sm[3];
    float S2 = sm[4] + sm[5] + sm[6] + sm[7];
    float mean = S1 * (1.0f / 1024.0f);
    float var = S2 * (1.0f / 1024.0f) - mean * mean;
    float rstd = rsqrtf(var + 1e-5f);
#pragma unroll
    for (int e = 0; e < 4; e++) {
        float o = (v[e] - mean) * rstd * lnw[e * 256 + d] + lnb[e * 256 + d];
        out[((size_t)e * BT_ + r) * 256 + d] = o;
    }
}

extern "C" void kernel_launch(void* const* d_in, const int* in_sizes, int n_in,
                              void* d_out, int out_size, void* d_ws, size_t ws_size,
                              hipStream_t stream)
{
    const float* x    = (const float*)d_in[0];
    const float* ipw  = (const float*)d_in[1];
    const float* ipb  = (const float*)d_in[2];
    const float* plog = (const float*)d_in[3];
    const float* mw   = (const float*)d_in[4];
    const float* mb   = (const float*)d_in[5];
    const float* fw1  = (const float*)d_in[6];
    const float* fb1  = (const float*)d_in[7];
    const float* fw2  = (const float*)d_in[8];
    const float* fb2  = (const float*)d_in[9];
    const float* lnw  = (const float*)d_in[10];
    const float* lnb  = (const float*)d_in[11];
    float* out = (float*)d_out;

    // Workspace (u16 elem offsets; ~99.5 MiB):
    //   buf_u    [0,          33,554,432)  scan buffer (E,BT,2,D) bf16, later h2
    //   buf_out  [33,554,432, 50,331,648)  mid output bf16; ALIASED early by:
    //              xc (bf16 x, 4,194,304) at 33,554,432   [dead after in_proj]
    //              carry (float2, 4 MiB)  at 37,748,736   [dead after scan_c]
    //   buf_mw_t [50,331,648, 50,855,936)  [e][o][c*256+d] stacked, sign-folded
    //   c_ipw_t  [50,855,936, 51,642,368)  [z][o][i]
    //   c_fw1_t  [51,642,368, 51,904,512)  [e][o][d]
    //   c_fw2_t  [51,904,512, 52,166,656)  [e][o][d]
    // d_out bytes [0, 33.5 MB) double as bf16 scratch for `o` then `h1`.
    u16* W = (u16*)d_ws;
    u16* buf_u    = W;
    u16* buf_out  = W + (size_t)33554432;
    u16* xc       = W + (size_t)33554432;
    float2* carry = (float2*)(W + (size_t)37748736);
    u16* buf_mw_t = W + (size_t)50331648;
    u16* c_ipw_t  = W + (size_t)50855936;
    u16* c_fw1_t  = W + (size_t)51642368;
    u16* c_fw2_t  = W + (size_t)51904512;
    u16* scratch  = (u16*)d_out;

    conv_k<<<2048, 256, 0, stream>>>(x, xc);
    prep_w<<<448, 256, 0, stream>>>(ipw, mw, fw1, fw2, c_ipw_t, buf_mw_t, c_fw1_t, c_fw2_t);
    // in_proj: u0,u1 (gamma-scaled, interleaved) -> buf_u ; o -> d_out scratch
    gemm_k<<<dim3(64, 4, 12), 256, 0, stream>>>(xc, c_ipw_t, ipb, nullptr, plog, buf_u, scratch, 256, 1, 1);
    // LRU scan (chunked, 3 phases), in-place in buf_u (xc dead now); hidden fused into scan_c
    scan_a<<<dim3(32, CHUNKS), 256, 0, stream>>>(buf_u, plog, carry);
    scan_b<<<64, 256, 0, stream>>>(plog, carry);
    scan_c<<<dim3(32, CHUNKS), 256, 0, stream>>>(buf_u, plog, carry, out);
    // mid (K=512 fused r/i) + o -> buf_out   (carry dead now)
    gemm_k<<<dim3(64, 4, 4), 256, 0, stream>>>(buf_u, buf_mw_t, mb, scratch, nullptr, buf_out, nullptr, 512, 2, 1);
    // ff1 + gelu -> d_out scratch (h1; `o` dead)
    gemm_k<<<dim3(64, 4, 4), 256, 0, stream>>>(buf_out, c_fw1_t, fb1, nullptr, nullptr, scratch, nullptr, 256, 3, 1);
    // ff2 + residual -> buf_u (h2 plain; scan data dead)
    gemm_k<<<dim3(64, 4, 4), 256, 0, stream>>>(scratch, c_fw2_t, fb2, buf_out, nullptr, buf_u, nullptr, 256, 4, 1);
    // layernorm across (e,d) -> d_out fp32 (overwrites scratch region last)
    ln_k<<<16384, 256, 0, stream>>>(buf_u, lnw, lnb, out);
}

// Round 10
// 335.396 us; speedup vs baseline: 1.3556x; 1.3281x over previous
//
#include <hip/hip_runtime.h>
#include <stdint.h>

#define BT_ 16384   // B*T
#define TT  1024
#define CHUNKS 32
#define CLEN   32
#define LANES  16384  // E*B*D

typedef __bf16 bf16x8 __attribute__((ext_vector_type(8)));
typedef float  f32x4  __attribute__((ext_vector_type(4)));
typedef unsigned int u32x4 __attribute__((ext_vector_type(4)));
typedef unsigned int u32x2 __attribute__((ext_vector_type(2)));
typedef unsigned short u16;

__device__ __forceinline__ float b2f(u16 s){
    union { float f; unsigned int u; } c; c.u = ((unsigned int)s) << 16; return c.f;
}
__device__ __forceinline__ u16 f2b(float f){
    union { float f; unsigned int u; } c; c.f = f;
    unsigned int u = c.u;
    return (u16)((u + 0x7fffu + ((u >> 16) & 1u)) >> 16);
}

// async global->LDS, 16 B per lane; LDS dest is wave-uniform base + lane*16
__device__ __forceinline__ void gload_lds16(const u16* g, u16* lds){
    __builtin_amdgcn_global_load_lds(
        (const __attribute__((address_space(1))) void*)g,
        (__attribute__((address_space(3))) void*)lds, 16, 0, 0);
}

// ---------------------------------------------------------------------------
// x: fp32 -> bf16 (A operand of in_proj), 8 elems/thread, 16B stores
// ---------------------------------------------------------------------------
__global__ __launch_bounds__(256) void conv_k(const float* __restrict__ x, u16* __restrict__ xc)
{
    long i = ((long)blockIdx.x * 256 + threadIdx.x) * 8;   // < 4,194,304
    float4 v0 = *reinterpret_cast<const float4*>(x + i);
    float4 v1 = *reinterpret_cast<const float4*>(x + i + 4);
    union { u16 s[8]; u32x4 v; } p;
    p.s[0] = f2b(v0.x); p.s[1] = f2b(v0.y); p.s[2] = f2b(v0.z); p.s[3] = f2b(v0.w);
    p.s[4] = f2b(v1.x); p.s[5] = f2b(v1.y); p.s[6] = f2b(v1.z); p.s[7] = f2b(v1.w);
    *reinterpret_cast<u32x4*>(xc + i) = p.v;
}

// ---------------------------------------------------------------------------
// Weight prep: fp32 -> bf16, TRANSPOSED to [n][k].
// 28 source matrices of 256x256 ([i][o], o contiguous):
//   w in [0,12)  : in_proj (z=k3*4+e)      -> c_ipw_t + w*65536          , ostride 256
//   w in [12,20) : mid (c=(w-12)>>2,e=&3)  -> buf_mw_t + e*131072 + c*256, ostride 512, sign -1 for c=1
//   w in [20,24) : ff_w1 (e)               -> c_fw1_t + e*65536          , ostride 256
//   w in [24,28) : ff_w2 (e)               -> c_fw2_t + e*65536          , ostride 256
// ---------------------------------------------------------------------------
__global__ __launch_bounds__(256) void prep_w(
    const float* __restrict__ ipw, const float* __restrict__ mw,
    const float* __restrict__ fw1, const float* __restrict__ fw2,
    u16* __restrict__ d_ipw, u16* __restrict__ d_mw,
    u16* __restrict__ d_fw1, u16* __restrict__ d_fw2)
{
    __shared__ u16 tile[64][72];
    int blk = blockIdx.x;            // < 448
    int w = blk >> 4, t = blk & 15;
    int tr = (t >> 2) * 64;          // i origin
    int tc = (t & 3) * 64;           // o origin
    const float* src; u16* dst; int ostride; float sign = 1.f;
    if (w < 12)      { src = ipw + (size_t)w * 65536; dst = d_ipw + (size_t)w * 65536; ostride = 256; }
    else if (w < 20) { int u = w - 12, c = u >> 2, e = u & 3;
                       src = mw + (size_t)u * 65536;
                       dst = d_mw + (size_t)e * 131072 + c * 256; ostride = 512;
                       if (c) sign = -1.f; }
    else if (w < 24) { int e = w - 20; src = fw1 + (size_t)e * 65536; dst = d_fw1 + (size_t)e * 65536; ostride = 256; }
    else             { int e = w - 24; src = fw2 + (size_t)e * 65536; dst = d_fw2 + (size_t)e * 65536; ostride = 256; }

    int q = threadIdx.x;
    int r = q >> 2, cb = (q & 3) * 16;
#pragma unroll
    for (int j = 0; j < 4; j++) {
        int col = cb + j * 4;
        const float4 v = *reinterpret_cast<const float4*>(src + (size_t)(tr + r) * 256 + tc + col);
        tile[r][col + 0] = f2b(v.x * sign);
        tile[r][col + 1] = f2b(v.y * sign);
        tile[r][col + 2] = f2b(v.z * sign);
        tile[r][col + 3] = f2b(v.w * sign);
    }
    __syncthreads();
    int ol = q >> 2, ib = (q & 3) * 16;
    union { u16 s[8]; u32x4 v; } p0, p1;
#pragma unroll
    for (int k = 0; k < 8; k++) { p0.s[k] = tile[ib + k][ol]; p1.s[k] = tile[ib + 8 + k][ol]; }
    u16* drow = dst + (size_t)(tc + ol) * ostride + tr + ib;
    *reinterpret_cast<u32x4*>(drow)     = p0.v;
    *reinterpret_cast<u32x4*>(drow + 8) = p1.v;
}

// ---------------------------------------------------------------------------
// Barrier-light GEMM: C[16384 x 256] = A[M x K] * B^T[N x K].
// Block covers MT m-tiles of 256 rows x 64 n-cols, SAME B panel (64 x 256K
// half = 32 KB LDS, chunk-swizzled phys = c ^ (row&7)).
//   K=256: B staged ONCE per block, reused across MT tiles (amortizes the
//          stage+drain barrier; r6-measured best).
//   K=512: B half restaged per (mt,kh).
// Wave: 64 m-rows (4 sets of 16) x 64 cols; acc[4][4] (64 accum regs).
// OPERAND-SWAPPED MFMA: mfma(Bfrag, Afrag) = D^T: lane owns m-row l16 with
// 4 CONSECUTIVE n-cols per acc reg set.
// K-loop: BOTH A and B fragments use explicit cur/next register prefetch —
// kt+1's 4 B ds_reads and 4 A global loads issue before kt's 16 MFMAs, so
// the ~120cy lgkm latency hides under the ~78cy MFMA burst (at 3 blk/CU
// there aren't enough waves to hide it by TLP alone; r6 pipes all <25%).
// REGISTER BUDGET (r4/r7/r9 lesson): __launch_bounds__(256,4) caps unified
// VGPR+AGPR at 128 -> acc(64 AGPR) leaves 64 VGPR -> A/B windows SPILL to
// scratch = +120 MB HBM write +70 MB fetch (VGPR_Count=64 is the tell).
// (256,3) gives ~170: acc 64 + A 32 + B 32 + addr ~12 fits. 3 blocks/CU.
// Epilogue — HW rule (r3/r4/r6/r7): global stores must cover FULL 128-B
// lines within ONE instruction. Per 16-row set, TWO 8-row passes through
// per-wave fs[8][64] f32 (2 KB/wave):
//   write: HALF-WAVE (lanes l16>>3==p) stage 4 acc f32x4, slot
//          phys=(nf*4+quad)^(l16&7)
//   read:  all 64 lanes (row=lane>>3, ch=lane&7), logical slots 2ch,2ch+1
//   store: 16 B/lane, 8 lanes/row -> full 128-B lines. Aux loads 16 B.
// r8 lesson: conditional write + same-address reads across passes lets LLVM
// CSE the reads (cross-lane LDS writes invisible per-thread) -> zero-cost
// compiler fences asm volatile("" ::: "memory") around the exchange.
// bias/gamma: <=4 named f32x4 regs loaded once (r5 lesson: no arrays).
// LDS: Bs 32KB + fs 8KB = 40KB. __launch_bounds__(256,3).
// mode 1: in_proj  z=(k3*4+e): k3<2 -> out0 interleaved *gamma +bias ; k3==2 -> out1 plain +bias
// mode 2: mid      z=e: + (mid_b0-mid_b1) + aux(o) -> out0
// mode 3: ff1      z=e: +bias, exact gelu -> out0
// mode 4: ff2      z=e: +bias + aux(residual) -> out0
// ---------------------------------------------------------------------------
__global__ __launch_bounds__(256, 3) void gemm_k(
    const u16* __restrict__ A0, const u16* __restrict__ B0,
    const float* __restrict__ biasf, const u16* __restrict__ aux,
    const float* __restrict__ gamlogf, u16* __restrict__ out0,
    u16* __restrict__ out1, int K, int mode, int MT)
{
    __shared__ __align__(16) u16 Bs[64 * 256];      // 32 KB, [n][k-half], swizzled 16B chunks
    __shared__ __align__(16) float fs_all[4][512];  // 8 KB, per-wave [8 rows][64 cols] f32

    int tid  = threadIdx.x;
    int wave = tid >> 6, lane = tid & 63;
    int quad = lane >> 4, l16 = lane & 15;
    int n0 = blockIdx.y * 64;
    int z = blockIdx.z;
    int e, k3 = 0;
    const u16* A;
    const u16* Bm;
    if (mode == 1) { k3 = z >> 2; e = z & 3; A = A0; }
    else           { e = z; A = A0 + (size_t)e * BT_ * K; }
    Bm = B0 + (size_t)(mode == 1 ? z : e) * 256 * K;

    int srow = lane >> 5, schunk = lane & 31;   // staging: 2 rows x 32 chunks / instr
    int nhalf = K >> 8;                          // 1 (K=256) or 2 (K=512)

    float* fsw = fs_all[wave];
    int rl8 = lane >> 3, ch = lane & 7;

    // readback constants: lane covers cols colb..colb+7 for ALL passes/sets
    // -> 4 named f32x4 registers, loaded once (r5 lesson: no arrays)
    int colb = n0 + ch * 8;
    f32x4 bias_lo, bias_hi;
    f32x4 gam_lo = (f32x4){1.f, 1.f, 1.f, 1.f}, gam_hi = gam_lo;
    if (mode == 1) {
        bias_lo = *reinterpret_cast<const f32x4*>(biasf + z * 256 + colb);
        bias_hi = *reinterpret_cast<const f32x4*>(biasf + z * 256 + colb + 4);
        if (k3 < 2) {
            f32x4 gl = *reinterpret_cast<const f32x4*>(gamlogf + 2048 + e * 256 + colb);
            f32x4 gh = *reinterpret_cast<const f32x4*>(gamlogf + 2048 + e * 256 + colb + 4);
#pragma unroll
            for (int r = 0; r < 4; r++) { gam_lo[r] = expf(gl[r]); gam_hi[r] = expf(gh[r]); }
        }
    } else if (mode == 2) {
        f32x4 a0 = *reinterpret_cast<const f32x4*>(biasf + e * 256 + colb);
        f32x4 a1 = *reinterpret_cast<const f32x4*>(biasf + e * 256 + colb + 4);
        f32x4 c0 = *reinterpret_cast<const f32x4*>(biasf + 1024 + e * 256 + colb);
        f32x4 c1 = *reinterpret_cast<const f32x4*>(biasf + 1024 + e * 256 + colb + 4);
        bias_lo = a0 - c0; bias_hi = a1 - c1;
    } else {
        bias_lo = *reinterpret_cast<const f32x4*>(biasf + e * 256 + colb);
        bias_hi = *reinterpret_cast<const f32x4*>(biasf + e * 256 + colb + 4);
    }

    for (int mt = 0; mt < MT; mt++) {
        int m0 = (blockIdx.x * MT + mt) * 256;

        f32x4 acc[4][4];
#pragma unroll
        for (int i = 0; i < 4; i++)
#pragma unroll
            for (int j = 0; j < 4; j++) acc[i][j] = (f32x4){0.f, 0.f, 0.f, 0.f};

        for (int kh = 0; kh < nhalf; kh++) {
            if (nhalf > 1 || mt == 0) {          // (re)stage B panel half
                if (mt || kh) __syncthreads();   // readers of previous content done
#pragma unroll
                for (int i = 0; i < 8; i++) {
                    int row = wave * 16 + i * 2 + srow;
                    int c = schunk ^ (row & 7);
                    gload_lds16(Bm + (size_t)(n0 + row) * K + kh * 256 + c * 8,
                                &Bs[(wave * 16 + i * 2) * 256]);
                }
                __syncthreads();                 // drains staging DMA (vmcnt 0)
            }

            const u16* Ar0 = A + (size_t)(m0 + wave * 64 + l16) * K + kh * 256 + quad * 8;
            const u16* Ar1 = Ar0 + (size_t)16 * K;
            const u16* Ar2 = Ar0 + (size_t)32 * K;
            const u16* Ar3 = Ar0 + (size_t)48 * K;

            // A cur/next window
            bf16x8 ac0, ac1, ac2, ac3, an0, an1, an2, an3;
            { union { u32x4 v; bf16x8 b; } u;
              u.v = *reinterpret_cast<const u32x4*>(Ar0); ac0 = u.b;
              u.v = *reinterpret_cast<const u32x4*>(Ar1); ac1 = u.b;
              u.v = *reinterpret_cast<const u32x4*>(Ar2); ac2 = u.b;
              u.v = *reinterpret_cast<const u32x4*>(Ar3); ac3 = u.b; }
            // B cur/next window (ds_read latency hidden under previous kt's MFMAs)
            bf16x8 bc0, bc1, bc2, bc3, bn0, bn1, bn2, bn3;
            {
#pragma unroll
                for (int nf = 0; nf < 4; nf++) {
                    int row = nf * 16 + l16;
                    int c = quad ^ (row & 7);    // kt=0
                    union { u32x4 v; bf16x8 b; } u;
                    u.v = *reinterpret_cast<const u32x4*>(&Bs[row * 256 + c * 8]);
                    if (nf == 0) bc0 = u.b; else if (nf == 1) bc1 = u.b;
                    else if (nf == 2) bc2 = u.b; else bc3 = u.b;
                }
            }
#pragma unroll
            for (int kt = 0; kt < 8; kt++) {
                if (kt < 7) {
                    union { u32x4 v; bf16x8 b; } u;
                    u.v = *reinterpret_cast<const u32x4*>(Ar0 + (kt + 1) * 32); an0 = u.b;
                    u.v = *reinterpret_cast<const u32x4*>(Ar1 + (kt + 1) * 32); an1 = u.b;
                    u.v = *reinterpret_cast<const u32x4*>(Ar2 + (kt + 1) * 32); an2 = u.b;
                    u.v = *reinterpret_cast<const u32x4*>(Ar3 + (kt + 1) * 32); an3 = u.b;
#pragma unroll
                    for (int nf = 0; nf < 4; nf++) {
                        int row = nf * 16 + l16;
                        int c = ((kt + 1) * 4 + quad) ^ (row & 7);
                        union { u32x4 v; bf16x8 b; } w;
                        w.v = *reinterpret_cast<const u32x4*>(&Bs[row * 256 + c * 8]);
                        if (nf == 0) bn0 = w.b; else if (nf == 1) bn1 = w.b;
                        else if (nf == 2) bn2 = w.b; else bn3 = w.b;
                    }
                }
                // swapped operands: D^T — lane = m-row, regs = 4 consecutive n-cols
                acc[0][0] = __builtin_amdgcn_mfma_f32_16x16x32_bf16(bc0, ac0, acc[0][0], 0, 0, 0);
                acc[1][0] = __builtin_amdgcn_mfma_f32_16x16x32_bf16(bc0, ac1, acc[1][0], 0, 0, 0);
                acc[2][0] = __builtin_amdgcn_mfma_f32_16x16x32_bf16(bc0, ac2, acc[2][0], 0, 0, 0);
                acc[3][0] = __builtin_amdgcn_mfma_f32_16x16x32_bf16(bc0, ac3, acc[3][0], 0, 0, 0);
                acc[0][1] = __builtin_amdgcn_mfma_f32_16x16x32_bf16(bc1, ac0, acc[0][1], 0, 0, 0);
                acc[1][1] = __builtin_amdgcn_mfma_f32_16x16x32_bf16(bc1, ac1, acc[1][1], 0, 0, 0);
                acc[2][1] = __builtin_amdgcn_mfma_f32_16x16x32_bf16(bc1, ac2, acc[2][1], 0, 0, 0);
                acc[3][1] = __builtin_amdgcn_mfma_f32_16x16x32_bf16(bc1, ac3, acc[3][1], 0, 0, 0);
                acc[0][2] = __builtin_amdgcn_mfma_f32_16x16x32_bf16(bc2, ac0, acc[0][2], 0, 0, 0);
                acc[1][2] = __builtin_amdgcn_mfma_f32_16x16x32_bf16(bc2, ac1, acc[1][2], 0, 0, 0);
                acc[2][2] = __builtin_amdgcn_mfma_f32_16x16x32_bf16(bc2, ac2, acc[2][2], 0, 0, 0);
                acc[3][2] = __builtin_amdgcn_mfma_f32_16x16x32_bf16(bc2, ac3, acc[3][2], 0, 0, 0);
                acc[0][3] = __builtin_amdgcn_mfma_f32_16x16x32_bf16(bc3, ac0, acc[0][3], 0, 0, 0);
                acc[1][3] = __builtin_amdgcn_mfma_f32_16x16x32_bf16(bc3, ac1, acc[1][3], 0, 0, 0);
                acc[2][3] = __builtin_amdgcn_mfma_f32_16x16x32_bf16(bc3, ac2, acc[2][3], 0, 0, 0);
                acc[3][3] = __builtin_amdgcn_mfma_f32_16x16x32_bf16(bc3, ac3, acc[3][3], 0, 0, 0);
                ac0 = an0; ac1 = an1; ac2 = an2; ac3 = an3;
                bc0 = bn0; bc1 = bn1; bc2 = bn2; bc3 = bn3;
            }
        }

        // epilogue: per 16-row set s, two 8-row passes through fs[8][64]
#pragma unroll
        for (int s = 0; s < 4; s++) {
#pragma unroll
            for (int p = 0; p < 2; p++) {
                if ((l16 >> 3) == p) {
#pragma unroll
                    for (int nf = 0; nf < 4; nf++) {
                        int phys = (nf * 4 + quad) ^ (l16 & 7);
                        *reinterpret_cast<f32x4*>(fsw + (l16 & 7) * 64 + phys * 4) = acc[s][nf];
                    }
                }
                // compiler fence: forbid CSE/reorder of the cross-lane LDS
                // exchange (r8 failure); emits no instruction, HW DS pipe is
                // in-order per wave.
                asm volatile("" ::: "memory");
                int pa = (2 * ch) ^ rl8;
                f32x4 lo = *reinterpret_cast<const f32x4*>(fsw + rl8 * 64 + pa * 4);
                f32x4 hi = *reinterpret_cast<const f32x4*>(fsw + rl8 * 64 + (pa ^ 1) * 4);
                asm volatile("" ::: "memory");
                lo += bias_lo; hi += bias_hi;
                if (mode == 1) { lo *= gam_lo; hi *= gam_hi; }
                if (mode == 3) {
#pragma unroll
                    for (int r = 0; r < 4; r++) {
                        lo[r] = 0.5f * lo[r] * (1.0f + erff(lo[r] * 0.70710678118654752f));
                        hi[r] = 0.5f * hi[r] * (1.0f + erff(hi[r] * 0.70710678118654752f));
                    }
                }
                int grow = m0 + wave * 64 + s * 16 + p * 8 + rl8;
                u16* dstp;
                if (mode == 1) {
                    if (k3 < 2) dstp = out0 + (((size_t)(e * BT_ + grow)) * 2 + k3) * 256 + colb;
                    else        dstp = out1 + ((size_t)e * BT_ + grow) * 256 + colb;
                } else {
                    dstp = out0 + ((size_t)e * BT_ + grow) * 256 + colb;
                }
                if (mode == 2 || mode == 4) {
                    const u16* ap = aux + ((size_t)e * BT_ + grow) * 256 + colb;
                    u32x4 av = *reinterpret_cast<const u32x4*>(ap);
                    lo[0] += b2f((u16)(av[0] & 0xffffu)); lo[1] += b2f((u16)(av[0] >> 16));
                    lo[2] += b2f((u16)(av[1] & 0xffffu)); lo[3] += b2f((u16)(av[1] >> 16));
                    hi[0] += b2f((u16)(av[2] & 0xffffu)); hi[1] += b2f((u16)(av[2] >> 16));
                    hi[2] += b2f((u16)(av[3] & 0xffffu)); hi[3] += b2f((u16)(av[3] >> 16));
                }
                u32x4 pv;
                pv[0] = (unsigned int)f2b(lo[0]) | ((unsigned int)f2b(lo[1]) << 16);
                pv[1] = (unsigned int)f2b(lo[2]) | ((unsigned int)f2b(lo[3]) << 16);
                pv[2] = (unsigned int)f2b(hi[0]) | ((unsigned int)f2b(hi[1]) << 16);
                pv[3] = (unsigned int)f2b(hi[2]) | ((unsigned int)f2b(hi[3]) << 16);
                *reinterpret_cast<u32x4*>(dstp) = pv;
            }
        }
    }
}

// ---------------------------------------------------------------------------
// LRU scan, 3 phases, 2 d-lanes per thread (u32 loads/stores).
// buf_u layout: ((e*BT + b*T + t)*2 + c)*256 + d  (c=0:re, 1:im)
// ---------------------------------------------------------------------------
__global__ __launch_bounds__(256) void scan_a(const u16* __restrict__ u,
    const float* __restrict__ plog, float2* __restrict__ carry)
{
    int l2 = blockIdx.x * 256 + threadIdx.x;      // < 8192
    int chunk = blockIdx.y;
    int dd = (l2 & 127) * 2, b = (l2 >> 7) & 15, e = l2 >> 11;
    float nu0 = expf(plog[e * 256 + dd]),        nu1 = expf(plog[e * 256 + dd + 1]);
    float th0 = expf(plog[1024 + e * 256 + dd]), th1 = expf(plog[1024 + e * 256 + dd + 1]);
    float m0 = expf(-nu0), m1 = expf(-nu1);
    float fr0 = m0 * cosf(th0), fi0 = m0 * sinf(th0);
    float fr1 = m1 * cosf(th1), fi1 = m1 * sinf(th1);
    size_t base = ((size_t)e * BT_ + b * TT) * 512 + (size_t)chunk * CLEN * 512 + dd;
    float hr0 = 0.f, hi0 = 0.f, hr1 = 0.f, hi1 = 0.f;
    for (int t = 0; t < CLEN; t++) {
        unsigned int wr = *reinterpret_cast<const unsigned int*>(u + base);
        unsigned int wi = *reinterpret_cast<const unsigned int*>(u + base + 256);
        float ur0 = b2f((u16)wr), ur1 = b2f((u16)(wr >> 16));
        float ui0 = b2f((u16)wi), ui1 = b2f((u16)(wi >> 16));
        float a0 = fr0 * hr0 - fi0 * hi0 + ur0;
        float b0 = fr0 * hi0 + fi0 * hr0 + ui0;
        float a1 = fr1 * hr1 - fi1 * hi1 + ur1;
        float b1 = fr1 * hi1 + fi1 * hr1 + ui1;
        hr0 = a0; hi0 = b0; hr1 = a1; hi1 = b1;
        base += 512;
    }
    size_t ci = (size_t)chunk * LANES + (size_t)e * 4096 + b * 256 + dd;
    *reinterpret_cast<float4*>(&carry[ci]) = make_float4(hr0, hi0, hr1, hi1);
}

__global__ __launch_bounds__(256) void scan_b(const float* __restrict__ plog,
                                              float2* __restrict__ carry)
{
    int l = blockIdx.x * 256 + threadIdx.x;
    int d = l & 255, e = l >> 12;
    float nu = expf(plog[e * 256 + d]);
    float th = expf(plog[1024 + e * 256 + d]);
    float magL = expf(-nu * (float)CLEN);
    float ang = th * (float)CLEN;
    float frL = magL * cosf(ang), fiL = magL * sinf(ang);
    float gr = 0.f, gi = 0.f;
    for (int j = 0; j < CHUNKS; j++) {
        float2 c = carry[(size_t)j * LANES + l];
        carry[(size_t)j * LANES + l] = make_float2(gr, gi);
        float gr2 = frL * gr - fiL * gi + c.x;
        float gi2 = frL * gi + fiL * gr + c.y;
        gr = gr2; gi = gi2;
    }
}

// scan_c also writes hidden (fp32, exact) on the last chunk.
__global__ __launch_bounds__(256) void scan_c(u16* __restrict__ u,
    const float* __restrict__ plog, const float2* __restrict__ carry,
    float* __restrict__ outh)
{
    int l2 = blockIdx.x * 256 + threadIdx.x;      // < 8192
    int chunk = blockIdx.y;
    int dd = (l2 & 127) * 2, b = (l2 >> 7) & 15, e = l2 >> 11;
    float nu0 = expf(plog[e * 256 + dd]),        nu1 = expf(plog[e * 256 + dd + 1]);
    float th0 = expf(plog[1024 + e * 256 + dd]), th1 = expf(plog[1024 + e * 256 + dd + 1]);
    float m0 = expf(-nu0), m1 = expf(-nu1);
    float fr0 = m0 * cosf(th0), fi0 = m0 * sinf(th0);
    float fr1 = m1 * cosf(th1), fi1 = m1 * sinf(th1);
    size_t base = ((size_t)e * BT_ + b * TT) * 512 + (size_t)chunk * CLEN * 512 + dd;
    size_t ci = (size_t)chunk * LANES + (size_t)e * 4096 + b * 256 + dd;
    float4 c0 = *reinterpret_cast<const float4*>(&carry[ci]);
    float hr0 = c0.x, hi0 = c0.y, hr1 = c0.z, hi1 = c0.w;
    for (int t = 0; t < CLEN; t++) {
        unsigned int wr = *reinterpret_cast<const unsigned int*>(u + base);
        unsigned int wi = *reinterpret_cast<const unsigned int*>(u + base + 256);
        float ur0 = b2f((u16)wr), ur1 = b2f((u16)(wr >> 16));
        float ui0 = b2f((u16)wi), ui1 = b2f((u16)(wi >> 16));
        float a0 = fr0 * hr0 - fi0 * hi0 + ur0;
        float b0 = fr0 * hi0 + fi0 * hr0 + ui0;
        float a1 = fr1 * hr1 - fi1 * hi1 + ur1;
        float b1 = fr1 * hi1 + fi1 * hr1 + ui1;
        hr0 = a0; hi0 = b0; hr1 = a1; hi1 = b1;
        *reinterpret_cast<unsigned int*>(u + base) =
            (unsigned int)f2b(hr0) | ((unsigned int)f2b(hr1) << 16);
        *reinterpret_cast<unsigned int*>(u + base + 256) =
            (unsigned int)f2b(hi0) | ((unsigned int)f2b(hi1) << 16);
        base += 512;
    }
    if (chunk == CHUNKS - 1) {
        float* oh = outh + (size_t)4 * BT_ * 256;
        *reinterpret_cast<float2*>(&oh[b * 2048 + e * 256 + dd])        = make_float2(hr0, hr1);
        *reinterpret_cast<float2*>(&oh[b * 2048 + 1024 + e * 256 + dd]) = make_float2(hi0, hi1);
    }
}

// LayerNorm across (e,d) per row r=(b,t); h2 plain (E, BT, D) bf16; fp32 out
__global__ __launch_bounds__(256) void ln_k(const u16* __restrict__ h2,
    const float* __restrict__ lnw, const float* __restrict__ lnb,
    float* __restrict__ out)
{
    int r = blockIdx.x;
    int d = threadIdx.x;
    float v[4]; float s1 = 0.f, s2 = 0.f;
#pragma unroll
    for (int e = 0; e < 4; e++) {
        float x = b2f(h2[((size_t)e * BT_ + r) * 256 + d]);
        v[e] = x; s1 += x; s2 += x * x;
    }
#pragma unroll
    for (int off = 32; off; off >>= 1) {
        s1 += __shfl_down(s1, off, 64);
        s2 += __shfl_down(s2, off, 64);
    }
    __shared__ float sm[8];
    int wave = threadIdx.x >> 6, lane = threadIdx.x & 63;
    if (lane == 0) { sm[wave] = s1; sm[4 + wave] = s2; }
    __syncthreads();
    float S1 = sm[0] + sm[1] + sm[2] + sm[3];
    float S2 = sm[4] + sm[5] + sm[6] + sm[7];
    float mean = S1 * (1.0f / 1024.0f);
    float var = S2 * (1.0f / 1024.0f) - mean * mean;
    float rstd = rsqrtf(var + 1e-5f);
#pragma unroll
    for (int e = 0; e < 4; e++) {
        float o = (v[e] - mean) * rstd * lnw[e * 256 + d] + lnb[e * 256 + d];
        out[((size_t)e * BT_ + r) * 256 + d] = o;
    }
}

extern "C" void kernel_launch(void* const* d_in, const int* in_sizes, int n_in,
                              void* d_out, int out_size, void* d_ws, size_t ws_size,
                              hipStream_t stream)
{
    const float* x    = (const float*)d_in[0];
    const float* ipw  = (const float*)d_in[1];
    const float* ipb  = (const float*)d_in[2];
    const float* plog = (const float*)d_in[3];
    const float* mw   = (const float*)d_in[4];
    const float* mb   = (const float*)d_in[5];
    const float* fw1  = (const float*)d_in[6];
    const float* fb1  = (const float*)d_in[7];
    const float* fw2  = (const float*)d_in[8];
    const float* fb2  = (const float*)d_in[9];
    const float* lnw  = (const float*)d_in[10];
    const float* lnb  = (const float*)d_in[11];
    float* out = (float*)d_out;

    // Workspace (u16 elem offsets; ~99.5 MiB):
    //   buf_u    [0,          33,554,432)  scan buffer (E,BT,2,D) bf16, later h2
    //   buf_out  [33,554,432, 50,331,648)  mid output bf16; ALIASED early by:
    //              xc (bf16 x, 4,194,304) at 33,554,432   [dead after in_proj]
    //              carry (float2, 4 MiB)  at 37,748,736   [dead after scan_c]
    //   buf_mw_t [50,331,648, 50,855,936)  [e][o][c*256+d] stacked, sign-folded
    //   c_ipw_t  [50,855,936, 51,642,368)  [z][o][i]
    //   c_fw1_t  [51,642,368, 51,904,512)  [e][o][d]
    //   c_fw2_t  [51,904,512, 52,166,656)  [e][o][d]
    // d_out bytes [0, 33.5 MB) double as bf16 scratch for `o` then `h1`.
    u16* W = (u16*)d_ws;
    u16* buf_u    = W;
    u16* buf_out  = W + (size_t)33554432;
    u16* xc       = W + (size_t)33554432;
    float2* carry = (float2*)(W + (size_t)37748736);
    u16* buf_mw_t = W + (size_t)50331648;
    u16* c_ipw_t  = W + (size_t)50855936;
    u16* c_fw1_t  = W + (size_t)51642368;
    u16* c_fw2_t  = W + (size_t)51904512;
    u16* scratch  = (u16*)d_out;

    conv_k<<<2048, 256, 0, stream>>>(x, xc);
    prep_w<<<448, 256, 0, stream>>>(ipw, mw, fw1, fw2, c_ipw_t, buf_mw_t, c_fw1_t, c_fw2_t);
    // in_proj: u0,u1 (gamma-scaled, interleaved) -> buf_u ; o -> d_out scratch
    gemm_k<<<dim3(16, 4, 12), 256, 0, stream>>>(xc, c_ipw_t, ipb, nullptr, plog, buf_u, scratch, 256, 1, 4);
    // LRU scan (chunked, 3 phases), in-place in buf_u (xc dead now); hidden fused into scan_c
    scan_a<<<dim3(32, CHUNKS), 256, 0, stream>>>(buf_u, plog, carry);
    scan_b<<<64, 256, 0, stream>>>(plog, carry);
    scan_c<<<dim3(32, CHUNKS), 256, 0, stream>>>(buf_u, plog, carry, out);
    // mid (K=512 fused r/i) + o -> buf_out   (carry dead now)
    gemm_k<<<dim3(32, 4, 4), 256, 0, stream>>>(buf_u, buf_mw_t, mb, scratch, nullptr, buf_out, nullptr, 512, 2, 2);
    // ff1 + gelu -> d_out scratch (h1; `o` dead)
    gemm_k<<<dim3(32, 4, 4), 256, 0, stream>>>(buf_out, c_fw1_t, fb1, nullptr, nullptr, scratch, nullptr, 256, 3, 2);
    // ff2 + residual -> buf_u (h2 plain; scan data dead)
    gemm_k<<<dim3(32, 4, 4), 256, 0, stream>>>(scratch, c_fw2_t, fb2, buf_out, nullptr, buf_u, nullptr, 256, 4, 2);
    // layernorm across (e,d) -> d_out fp32 (overwrites scratch region last)
    ln_k<<<16384, 256, 0, stream>>>(buf_u, lnw, lnb, out);
}

// Round 11
// 289.316 us; speedup vs baseline: 1.5716x; 1.1593x over previous
//
#include <hip/hip_runtime.h>
#include <stdint.h>

#define BT_ 16384   // B*T
#define TT  1024
#define CHUNKS 32
#define CLEN   32
#define LANES  16384  // E*B*D

typedef __bf16 bf16x8 __attribute__((ext_vector_type(8)));
typedef float  f32x4  __attribute__((ext_vector_type(4)));
typedef unsigned int u32x4 __attribute__((ext_vector_type(4)));
typedef unsigned short u16;

__device__ __forceinline__ float b2f(u16 s){
    union { float f; unsigned int u; } c; c.u = ((unsigned int)s) << 16; return c.f;
}
__device__ __forceinline__ u16 f2b(float f){
    union { float f; unsigned int u; } c; c.f = f;
    unsigned int u = c.u;
    return (u16)((u + 0x7fffu + ((u >> 16) & 1u)) >> 16);
}

// async global->LDS, 16 B per lane; LDS dest is wave-uniform base + lane*16
__device__ __forceinline__ void gload_lds16(const u16* g, u16* lds){
    __builtin_amdgcn_global_load_lds(
        (const __attribute__((address_space(1))) void*)g,
        (__attribute__((address_space(3))) void*)lds, 16, 0, 0);
}

// ---------------------------------------------------------------------------
// x: fp32 -> bf16 (A operand of in_proj), 8 elems/thread, 16B stores
// ---------------------------------------------------------------------------
__global__ __launch_bounds__(256) void conv_k(const float* __restrict__ x, u16* __restrict__ xc)
{
    long i = ((long)blockIdx.x * 256 + threadIdx.x) * 8;   // < 4,194,304
    float4 v0 = *reinterpret_cast<const float4*>(x + i);
    float4 v1 = *reinterpret_cast<const float4*>(x + i + 4);
    union { u16 s[8]; u32x4 v; } p;
    p.s[0] = f2b(v0.x); p.s[1] = f2b(v0.y); p.s[2] = f2b(v0.z); p.s[3] = f2b(v0.w);
    p.s[4] = f2b(v1.x); p.s[5] = f2b(v1.y); p.s[6] = f2b(v1.z); p.s[7] = f2b(v1.w);
    *reinterpret_cast<u32x4*>(xc + i) = p.v;
}

// ---------------------------------------------------------------------------
// Weight prep: fp32 -> bf16, TRANSPOSED to [n][k].
// 28 source matrices of 256x256 ([i][o], o contiguous):
//   w in [0,12)  : in_proj (z=k3*4+e)      -> c_ipw_t + w*65536          , ostride 256
//   w in [12,20) : mid (c=(w-12)>>2,e=&3)  -> buf_mw_t + e*131072 + c*256, ostride 512, sign -1 for c=1
//   w in [20,24) : ff_w1 (e)               -> c_fw1_t + e*65536          , ostride 256
//   w in [24,28) : ff_w2 (e)               -> c_fw2_t + e*65536          , ostride 256
// ---------------------------------------------------------------------------
__global__ __launch_bounds__(256) void prep_w(
    const float* __restrict__ ipw, const float* __restrict__ mw,
    const float* __restrict__ fw1, const float* __restrict__ fw2,
    u16* __restrict__ d_ipw, u16* __restrict__ d_mw,
    u16* __restrict__ d_fw1, u16* __restrict__ d_fw2)
{
    __shared__ u16 tile[64][72];
    int blk = blockIdx.x;            // < 448
    int w = blk >> 4, t = blk & 15;
    int tr = (t >> 2) * 64;          // i origin
    int tc = (t & 3) * 64;           // o origin
    const float* src; u16* dst; int ostride; float sign = 1.f;
    if (w < 12)      { src = ipw + (size_t)w * 65536; dst = d_ipw + (size_t)w * 65536; ostride = 256; }
    else if (w < 20) { int u = w - 12, c = u >> 2, e = u & 3;
                       src = mw + (size_t)u * 65536;
                       dst = d_mw + (size_t)e * 131072 + c * 256; ostride = 512;
                       if (c) sign = -1.f; }
    else if (w < 24) { int e = w - 20; src = fw1 + (size_t)e * 65536; dst = d_fw1 + (size_t)e * 65536; ostride = 256; }
    else             { int e = w - 24; src = fw2 + (size_t)e * 65536; dst = d_fw2 + (size_t)e * 65536; ostride = 256; }

    int q = threadIdx.x;
    int r = q >> 2, cb = (q & 3) * 16;
#pragma unroll
    for (int j = 0; j < 4; j++) {
        int col = cb + j * 4;
        const float4 v = *reinterpret_cast<const float4*>(src + (size_t)(tr + r) * 256 + tc + col);
        tile[r][col + 0] = f2b(v.x * sign);
        tile[r][col + 1] = f2b(v.y * sign);
        tile[r][col + 2] = f2b(v.z * sign);
        tile[r][col + 3] = f2b(v.w * sign);
    }
    __syncthreads();
    int ol = q >> 2, ib = (q & 3) * 16;
    union { u16 s[8]; u32x4 v; } p0, p1;
#pragma unroll
    for (int k = 0; k < 8; k++) { p0.s[k] = tile[ib + k][ol]; p1.s[k] = tile[ib + 8 + k][ol]; }
    u16* drow = dst + (size_t)(tc + ol) * ostride + tr + ib;
    *reinterpret_cast<u32x4*>(drow)     = p0.v;
    *reinterpret_cast<u32x4*>(drow + 8) = p1.v;
}

// ---------------------------------------------------------------------------
// m97-style full-LDS GEMM: C[16384 x 256] = A[M x K] * B^T[N x K].
// Block tile 128 m x 128 n; 4 waves (2x2); wave = 64x64, acc[4][4] (64 regs).
// K-loop in BK=64 steps: per step, BOTH A[128][64] and B[128][64] tiles are
// DMA'd via global_load_lds (16+16 KB, single-buffered, 2 barriers/step).
// Rationale (r1/r2/r9/r10 lesson): hipcc collapses every source-level
// register prefetch window (VGPR stays ~84), leaving A-loads 1-deep against
// ~500-900cy L2/L3 latency -> MfmaUtil stuck at 14%. The DMA engine gives
// latency depth without registers the compiler can discard.
// Chunk swizzle (8x16B chunks/row): phys = c ^ (row&7); DMA pre-swizzles the
// GLOBAL source chunk (LDS dest must stay linear: lane*16). Read side XORs
// the same mask. Same mapping as the proven B staging, 8-chunk rows.
// OPERAND-SWAPPED MFMA: mfma(Bfrag, Afrag) = D^T: lane owns m-row l16 with
// 4 CONSECUTIVE n-cols per acc reg set.
// Epilogue — HW rule (r3/r4/r6/r7): global stores must cover FULL 128-B
// lines within ONE instruction. Per 16-row set, TWO 8-row passes through
// per-wave fs[8][64] f32 (2 KB/wave):
//   write: HALF-WAVE (lanes l16>>3==p) stage 4 acc f32x4, slot
//          phys=(nf*4+quad)^(l16&7)
//   read:  all 64 lanes (row=lane>>3, ch=lane&7), logical slots 2ch,2ch+1
//   store: 16 B/lane, 8 lanes/row -> full 128-B lines. Aux loads 16 B.
// r8 lesson: conditional write + same-address reads across passes lets LLVM
// CSE the reads -> zero-cost asm volatile("" ::: "memory") fences.
// bias/gamma: <=4 named f32x4 regs loaded once (r5 lesson: no arrays).
// REGISTER BUDGET (r9 lesson): acc=64 needs the (256,3) 170-reg budget;
// (256,4)=128 spills to scratch (+120MB HBM, VGPR_Count=64 is the tell).
// LDS: As 16KB + Bs2 16KB + fs 8KB = 40KB. __launch_bounds__(256,3).
// mode 1: in_proj  z=(k3*4+e): k3<2 -> out0 interleaved *gamma +bias ; k3==2 -> out1 plain +bias
// mode 2: mid      z=e: + (mid_b0-mid_b1) + aux(o) -> out0
// mode 3: ff1      z=e: +bias, exact gelu -> out0
// mode 4: ff2      z=e: +bias + aux(residual) -> out0
// ---------------------------------------------------------------------------
__global__ __launch_bounds__(256, 3) void gemm_k(
    const u16* __restrict__ A0, const u16* __restrict__ B0,
    const float* __restrict__ biasf, const u16* __restrict__ aux,
    const float* __restrict__ gamlogf, u16* __restrict__ out0,
    u16* __restrict__ out1, int K, int mode)
{
    __shared__ __align__(16) u16 As [128 * 64];     // 16 KB, [m-row][k-chunk swz]
    __shared__ __align__(16) u16 Bs2[128 * 64];     // 16 KB, [n-row][k-chunk swz]
    __shared__ __align__(16) float fs_all[4][512];  // 8 KB, per-wave [8 rows][64 cols] f32

    int tid  = threadIdx.x;
    int wave = tid >> 6, lane = tid & 63;
    int quad = lane >> 4, l16 = lane & 15;
    int wm = wave >> 1, wn = wave & 1;
    int m0 = blockIdx.x * 128, n0 = blockIdx.y * 128;
    int z = blockIdx.z;
    int e, k3 = 0;
    const u16* A;
    const u16* Bm;
    if (mode == 1) { k3 = z >> 2; e = z & 3; A = A0; }
    else           { e = z; A = A0 + (size_t)e * BT_ * K; }
    Bm = B0 + (size_t)(mode == 1 ? z : e) * 256 * K;

    // DMA source/dest setup: each wave stages 32 rows of A and 32 of B
    // (4 instrs x 8 rows). lane l -> row +(l>>3), phys chunk (l&7); global
    // chunk pre-swizzled: (l&7)^(l>>3)  (rowbase % 8 == 0).
    int srow8 = lane >> 3, sch = lane & 7;
    int swc = sch ^ srow8;
    const u16* ag[4]; const u16* bg[4]; u16* al[4]; u16* bl[4];
#pragma unroll
    for (int i = 0; i < 4; i++) {
        int ra = wave * 32 + i * 8;
        ag[i] = A  + (size_t)(m0 + ra + srow8) * K + swc * 8;
        bg[i] = Bm + (size_t)(n0 + ra + srow8) * K + swc * 8;
        al[i] = As  + ra * 64;
        bl[i] = Bs2 + ra * 64;
    }

    float* fsw = fs_all[wave];
    int rl8 = lane >> 3, ch = lane & 7;

    // readback constants: lane covers cols colb..colb+7 (r5 lesson: no arrays)
    int colb = n0 + wn * 64 + ch * 8;
    f32x4 bias_lo, bias_hi;
    f32x4 gam_lo = (f32x4){1.f, 1.f, 1.f, 1.f}, gam_hi = gam_lo;
    if (mode == 1) {
        bias_lo = *reinterpret_cast<const f32x4*>(biasf + z * 256 + colb);
        bias_hi = *reinterpret_cast<const f32x4*>(biasf + z * 256 + colb + 4);
        if (k3 < 2) {
            f32x4 gl = *reinterpret_cast<const f32x4*>(gamlogf + 2048 + e * 256 + colb);
            f32x4 gh = *reinterpret_cast<const f32x4*>(gamlogf + 2048 + e * 256 + colb + 4);
#pragma unroll
            for (int r = 0; r < 4; r++) { gam_lo[r] = expf(gl[r]); gam_hi[r] = expf(gh[r]); }
        }
    } else if (mode == 2) {
        f32x4 a0 = *reinterpret_cast<const f32x4*>(biasf + e * 256 + colb);
        f32x4 a1 = *reinterpret_cast<const f32x4*>(biasf + e * 256 + colb + 4);
        f32x4 c0 = *reinterpret_cast<const f32x4*>(biasf + 1024 + e * 256 + colb);
        f32x4 c1 = *reinterpret_cast<const f32x4*>(biasf + 1024 + e * 256 + colb + 4);
        bias_lo = a0 - c0; bias_hi = a1 - c1;
    } else {
        bias_lo = *reinterpret_cast<const f32x4*>(biasf + e * 256 + colb);
        bias_hi = *reinterpret_cast<const f32x4*>(biasf + e * 256 + colb + 4);
    }

    f32x4 acc[4][4];
#pragma unroll
    for (int i = 0; i < 4; i++)
#pragma unroll
        for (int j = 0; j < 4; j++) acc[i][j] = (f32x4){0.f, 0.f, 0.f, 0.f};

    int nstep = K >> 6;
    for (int st = 0; st < nstep; ++st) {
        if (st) __syncthreads();                 // readers done with previous step
#pragma unroll
        for (int i = 0; i < 4; i++) {
            gload_lds16(ag[i], al[i]);
            gload_lds16(bg[i], bl[i]);
            ag[i] += 64; bg[i] += 64;            // advance one BK (64 elems)
        }
        __syncthreads();                         // drain staging DMA (vmcnt 0)

#pragma unroll
        for (int kt = 0; kt < 2; kt++) {
            bf16x8 afr[4], bfr[4];
#pragma unroll
            for (int f = 0; f < 4; f++) {
                int phys = (kt * 4 + quad) ^ (l16 & 7);
                int rowa = wm * 64 + f * 16 + l16;
                int rowb = wn * 64 + f * 16 + l16;
                union { u32x4 v; bf16x8 b; } u, w;
                u.v = *reinterpret_cast<const u32x4*>(As  + rowa * 64 + phys * 8);
                w.v = *reinterpret_cast<const u32x4*>(Bs2 + rowb * 64 + phys * 8);
                afr[f] = u.b; bfr[f] = w.b;
            }
            // swapped operands: D^T — lane = m-row, regs = 4 consecutive n-cols
#pragma unroll
            for (int i = 0; i < 4; i++)
#pragma unroll
                for (int j = 0; j < 4; j++)
                    acc[i][j] = __builtin_amdgcn_mfma_f32_16x16x32_bf16(bfr[j], afr[i], acc[i][j], 0, 0, 0);
        }
    }

    // epilogue: per 16-row set s, two 8-row passes through fs[8][64]
#pragma unroll
    for (int s = 0; s < 4; s++) {
#pragma unroll
        for (int p = 0; p < 2; p++) {
            if ((l16 >> 3) == p) {
#pragma unroll
                for (int nf = 0; nf < 4; nf++) {
                    int phys = (nf * 4 + quad) ^ (l16 & 7);
                    *reinterpret_cast<f32x4*>(fsw + (l16 & 7) * 64 + phys * 4) = acc[s][nf];
                }
            }
            // compiler fence: forbid CSE/reorder of the cross-lane LDS
            // exchange (r8 failure); emits no instruction.
            asm volatile("" ::: "memory");
            int pa = (2 * ch) ^ rl8;
            f32x4 lo = *reinterpret_cast<const f32x4*>(fsw + rl8 * 64 + pa * 4);
            f32x4 hi = *reinterpret_cast<const f32x4*>(fsw + rl8 * 64 + (pa ^ 1) * 4);
            asm volatile("" ::: "memory");
            lo += bias_lo; hi += bias_hi;
            if (mode == 1) { lo *= gam_lo; hi *= gam_hi; }
            if (mode == 3) {
#pragma unroll
                for (int r = 0; r < 4; r++) {
                    lo[r] = 0.5f * lo[r] * (1.0f + erff(lo[r] * 0.70710678118654752f));
                    hi[r] = 0.5f * hi[r] * (1.0f + erff(hi[r] * 0.70710678118654752f));
                }
            }
            int grow = m0 + wm * 64 + s * 16 + p * 8 + rl8;
            u16* dstp;
            if (mode == 1) {
                if (k3 < 2) dstp = out0 + (((size_t)(e * BT_ + grow)) * 2 + k3) * 256 + colb;
                else        dstp = out1 + ((size_t)e * BT_ + grow) * 256 + colb;
            } else {
                dstp = out0 + ((size_t)e * BT_ + grow) * 256 + colb;
            }
            if (mode == 2 || mode == 4) {
                const u16* ap = aux + ((size_t)e * BT_ + grow) * 256 + colb;
                u32x4 av = *reinterpret_cast<const u32x4*>(ap);
                lo[0] += b2f((u16)(av[0] & 0xffffu)); lo[1] += b2f((u16)(av[0] >> 16));
                lo[2] += b2f((u16)(av[1] & 0xffffu)); lo[3] += b2f((u16)(av[1] >> 16));
                hi[0] += b2f((u16)(av[2] & 0xffffu)); hi[1] += b2f((u16)(av[2] >> 16));
                hi[2] += b2f((u16)(av[3] & 0xffffu)); hi[3] += b2f((u16)(av[3] >> 16));
            }
            u32x4 pv;
            pv[0] = (unsigned int)f2b(lo[0]) | ((unsigned int)f2b(lo[1]) << 16);
            pv[1] = (unsigned int)f2b(lo[2]) | ((unsigned int)f2b(lo[3]) << 16);
            pv[2] = (unsigned int)f2b(hi[0]) | ((unsigned int)f2b(hi[1]) << 16);
            pv[3] = (unsigned int)f2b(hi[2]) | ((unsigned int)f2b(hi[3]) << 16);
            *reinterpret_cast<u32x4*>(dstp) = pv;
        }
    }
}

// ---------------------------------------------------------------------------
// LRU scan, 3 phases, 2 d-lanes per thread (u32 loads/stores).
// buf_u layout: ((e*BT + b*T + t)*2 + c)*256 + d  (c=0:re, 1:im)
// ---------------------------------------------------------------------------
__global__ __launch_bounds__(256) void scan_a(const u16* __restrict__ u,
    const float* __restrict__ plog, float2* __restrict__ carry)
{
    int l2 = blockIdx.x * 256 + threadIdx.x;      // < 8192
    int chunk = blockIdx.y;
    int dd = (l2 & 127) * 2, b = (l2 >> 7) & 15, e = l2 >> 11;
    float nu0 = expf(plog[e * 256 + dd]),        nu1 = expf(plog[e * 256 + dd + 1]);
    float th0 = expf(plog[1024 + e * 256 + dd]), th1 = expf(plog[1024 + e * 256 + dd + 1]);
    float m0 = expf(-nu0), m1 = expf(-nu1);
    float fr0 = m0 * cosf(th0), fi0 = m0 * sinf(th0);
    float fr1 = m1 * cosf(th1), fi1 = m1 * sinf(th1);
    size_t base = ((size_t)e * BT_ + b * TT) * 512 + (size_t)chunk * CLEN * 512 + dd;
    float hr0 = 0.f, hi0 = 0.f, hr1 = 0.f, hi1 = 0.f;
    for (int t = 0; t < CLEN; t++) {
        unsigned int wr = *reinterpret_cast<const unsigned int*>(u + base);
        unsigned int wi = *reinterpret_cast<const unsigned int*>(u + base + 256);
        float ur0 = b2f((u16)wr), ur1 = b2f((u16)(wr >> 16));
        float ui0 = b2f((u16)wi), ui1 = b2f((u16)(wi >> 16));
        float a0 = fr0 * hr0 - fi0 * hi0 + ur0;
        float b0 = fr0 * hi0 + fi0 * hr0 + ui0;
        float a1 = fr1 * hr1 - fi1 * hi1 + ur1;
        float b1 = fr1 * hi1 + fi1 * hr1 + ui1;
        hr0 = a0; hi0 = b0; hr1 = a1; hi1 = b1;
        base += 512;
    }
    size_t ci = (size_t)chunk * LANES + (size_t)e * 4096 + b * 256 + dd;
    *reinterpret_cast<float4*>(&carry[ci]) = make_float4(hr0, hi0, hr1, hi1);
}

__global__ __launch_bounds__(256) void scan_b(const float* __restrict__ plog,
                                              float2* __restrict__ carry)
{
    int l = blockIdx.x * 256 + threadIdx.x;
    int d = l & 255, e = l >> 12;
    float nu = expf(plog[e * 256 + d]);
    float th = expf(plog[1024 + e * 256 + d]);
    float magL = expf(-nu * (float)CLEN);
    float ang = th * (float)CLEN;
    float frL = magL * cosf(ang), fiL = magL * sinf(ang);
    float gr = 0.f, gi = 0.f;
    for (int j = 0; j < CHUNKS; j++) {
        float2 c = carry[(size_t)j * LANES + l];
        carry[(size_t)j * LANES + l] = make_float2(gr, gi);
        float gr2 = frL * gr - fiL * gi + c.x;
        float gi2 = frL * gi + fiL * gr + c.y;
        gr = gr2; gi = gi2;
    }
}

// scan_c also writes hidden (fp32, exact) on the last chunk.
__global__ __launch_bounds__(256) void scan_c(u16* __restrict__ u,
    const float* __restrict__ plog, const float2* __restrict__ carry,
    float* __restrict__ outh)
{
    int l2 = blockIdx.x * 256 + threadIdx.x;      // < 8192
    int chunk = blockIdx.y;
    int dd = (l2 & 127) * 2, b = (l2 >> 7) & 15, e = l2 >> 11;
    float nu0 = expf(plog[e * 256 + dd]),        nu1 = expf(plog[e * 256 + dd + 1]);
    float th0 = expf(plog[1024 + e * 256 + dd]), th1 = expf(plog[1024 + e * 256 + dd + 1]);
    float m0 = expf(-nu0), m1 = expf(-nu1);
    float fr0 = m0 * cosf(th0), fi0 = m0 * sinf(th0);
    float fr1 = m1 * cosf(th1), fi1 = m1 * sinf(th1);
    size_t base = ((size_t)e * BT_ + b * TT) * 512 + (size_t)chunk * CLEN * 512 + dd;
    size_t ci = (size_t)chunk * LANES + (size_t)e * 4096 + b * 256 + dd;
    float4 c0 = *reinterpret_cast<const float4*>(&carry[ci]);
    float hr0 = c0.x, hi0 = c0.y, hr1 = c0.z, hi1 = c0.w;
    for (int t = 0; t < CLEN; t++) {
        unsigned int wr = *reinterpret_cast<const unsigned int*>(u + base);
        unsigned int wi = *reinterpret_cast<const unsigned int*>(u + base + 256);
        float ur0 = b2f((u16)wr), ur1 = b2f((u16)(wr >> 16));
        float ui0 = b2f((u16)wi), ui1 = b2f((u16)(wi >> 16));
        float a0 = fr0 * hr0 - fi0 * hi0 + ur0;
        float b0 = fr0 * hi0 + fi0 * hr0 + ui0;
        float a1 = fr1 * hr1 - fi1 * hi1 + ur1;
        float b1 = fr1 * hi1 + fi1 * hr1 + ui1;
        hr0 = a0; hi0 = b0; hr1 = a1; hi1 = b1;
        *reinterpret_cast<unsigned int*>(u + base) =
            (unsigned int)f2b(hr0) | ((unsigned int)f2b(hr1) << 16);
        *reinterpret_cast<unsigned int*>(u + base + 256) =
            (unsigned int)f2b(hi0) | ((unsigned int)f2b(hi1) << 16);
        base += 512;
    }
    if (chunk == CHUNKS - 1) {
        float* oh = outh + (size_t)4 * BT_ * 256;
        *reinterpret_cast<float2*>(&oh[b * 2048 + e * 256 + dd])        = make_float2(hr0, hr1);
        *reinterpret_cast<float2*>(&oh[b * 2048 + 1024 + e * 256 + dd]) = make_float2(hi0, hi1);
    }
}

// LayerNorm across (e,d) per row r=(b,t); h2 plain (E, BT, D) bf16; fp32 out
__global__ __launch_bounds__(256) void ln_k(const u16* __restrict__ h2,
    const float* __restrict__ lnw, const float* __restrict__ lnb,
    float* __restrict__ out)
{
    int r = blockIdx.x;
    int d = threadIdx.x;
    float v[4]; float s1 = 0.f, s2 = 0.f;
#pragma unroll
    for (int e = 0; e < 4; e++) {
        float x = b2f(h2[((size_t)e * BT_ + r) * 256 + d]);
        v[e] = x; s1 += x; s2 += x * x;
    }
#pragma unroll
    for (int off = 32; off; off >>= 1) {
        s1 += __shfl_down(s1, off, 64);
        s2 += __shfl_down(s2, off, 64);
    }
    __shared__ float sm[8];
    int wave = threadIdx.x >> 6, lane = threadIdx.x & 63;
    if (lane == 0) { sm[wave] = s1; sm[4 + wave] = s2; }
    __syncthreads();
    float S1 = sm[0] + sm[1] + sm[2] + sm[3];
    float S2 = sm[4] + sm[5] + sm[6] + sm[7];
    float mean = S1 * (1.0f / 1024.0f);
    float var = S2 * (1.0f / 1024.0f) - mean * mean;
    float rstd = rsqrtf(var + 1e-5f);
#pragma unroll
    for (int e = 0; e < 4; e++) {
        float o = (v[e] - mean) * rstd * lnw[e * 256 + d] + lnb[e * 256 + d];
        out[((size_t)e * BT_ + r) * 256 + d] = o;
    }
}

extern "C" void kernel_launch(void* const* d_in, const int* in_sizes, int n_in,
                              void* d_out, int out_size, void* d_ws, size_t ws_size,
                              hipStream_t stream)
{
    const float* x    = (const float*)d_in[0];
    const float* ipw  = (const float*)d_in[1];
    const float* ipb  = (const float*)d_in[2];
    const float* plog = (const float*)d_in[3];
    const float* mw   = (const float*)d_in[4];
    const float* mb   = (const float*)d_in[5];
    const float* fw1  = (const float*)d_in[6];
    const float* fb1  = (const float*)d_in[7];
    const float* fw2  = (const float*)d_in[8];
    const float* fb2  = (const float*)d_in[9];
    const float* lnw  = (const float*)d_in[10];
    const float* lnb  = (const float*)d_in[11];
    float* out = (float*)d_out;

    // Workspace (u16 elem offsets; ~99.5 MiB):
    //   buf_u    [0,          33,554,432)  scan buffer (E,BT,2,D) bf16, later h2
    //   buf_out  [33,554,432, 50,331,648)  mid output bf16; ALIASED early by:
    //              xc (bf16 x, 4,194,304) at 33,554,432   [dead after in_proj]
    //              carry (float2, 4 MiB)  at 37,748,736   [dead after scan_c]
    //   buf_mw_t [50,331,648, 50,855,936)  [e][o][c*256+d] stacked, sign-folded
    //   c_ipw_t  [50,855,936, 51,642,368)  [z][o][i]
    //   c_fw1_t  [51,642,368, 51,904,512)  [e][o][d]
    //   c_fw2_t  [51,904,512, 52,166,656)  [e][o][d]
    // d_out bytes [0, 33.5 MB) double as bf16 scratch for `o` then `h1`.
    u16* W = (u16*)d_ws;
    u16* buf_u    = W;
    u16* buf_out  = W + (size_t)33554432;
    u16* xc       = W + (size_t)33554432;
    float2* carry = (float2*)(W + (size_t)37748736);
    u16* buf_mw_t = W + (size_t)50331648;
    u16* c_ipw_t  = W + (size_t)50855936;
    u16* c_fw1_t  = W + (size_t)51642368;
    u16* c_fw2_t  = W + (size_t)51904512;
    u16* scratch  = (u16*)d_out;

    conv_k<<<2048, 256, 0, stream>>>(x, xc);
    prep_w<<<448, 256, 0, stream>>>(ipw, mw, fw1, fw2, c_ipw_t, buf_mw_t, c_fw1_t, c_fw2_t);
    // in_proj: u0,u1 (gamma-scaled, interleaved) -> buf_u ; o -> d_out scratch
    gemm_k<<<dim3(128, 2, 12), 256, 0, stream>>>(xc, c_ipw_t, ipb, nullptr, plog, buf_u, scratch, 256, 1);
    // LRU scan (chunked, 3 phases), in-place in buf_u (xc dead now); hidden fused into scan_c
    scan_a<<<dim3(32, CHUNKS), 256, 0, stream>>>(buf_u, plog, carry);
    scan_b<<<64, 256, 0, stream>>>(plog, carry);
    scan_c<<<dim3(32, CHUNKS), 256, 0, stream>>>(buf_u, plog, carry, out);
    // mid (K=512 fused r/i) + o -> buf_out   (carry dead now)
    gemm_k<<<dim3(128, 2, 4), 256, 0, stream>>>(buf_u, buf_mw_t, mb, scratch, nullptr, buf_out, nullptr, 512, 2);
    // ff1 + gelu -> d_out scratch (h1; `o` dead)
    gemm_k<<<dim3(128, 2, 4), 256, 0, stream>>>(buf_out, c_fw1_t, fb1, nullptr, nullptr, scratch, nullptr, 256, 3);
    // ff2 + residual -> buf_u (h2 plain; scan data dead)
    gemm_k<<<dim3(128, 2, 4), 256, 0, stream>>>(scratch, c_fw2_t, fb2, buf_out, nullptr, buf_u, nullptr, 256, 4);
    // layernorm across (e,d) -> d_out fp32 (overwrites scratch region last)
    ln_k<<<16384, 256, 0, stream>>>(buf_u, lnw, lnb, out);
}

// Round 12
// 289.211 us; speedup vs baseline: 1.5721x; 1.0004x over previous
//
#include <hip/hip_runtime.h>
#include <stdint.h>

#define BT_ 16384   // B*T
#define TT  1024
#define CHUNKS 32
#define CLEN   32
#define LANES  16384  // E*B*D

typedef __bf16 bf16x8 __attribute__((ext_vector_type(8)));
typedef float  f32x4  __attribute__((ext_vector_type(4)));
typedef unsigned int u32x4 __attribute__((ext_vector_type(4)));
typedef unsigned short u16;

__device__ __forceinline__ float b2f(u16 s){
    union { float f; unsigned int u; } c; c.u = ((unsigned int)s) << 16; return c.f;
}
__device__ __forceinline__ u16 f2b(float f){
    union { float f; unsigned int u; } c; c.f = f;
    unsigned int u = c.u;
    return (u16)((u + 0x7fffu + ((u >> 16) & 1u)) >> 16);
}

// async global->LDS, 16 B per lane; LDS dest is wave-uniform base + lane*16
__device__ __forceinline__ void gload_lds16(const u16* g, u16* lds){
    __builtin_amdgcn_global_load_lds(
        (const __attribute__((address_space(1))) void*)g,
        (__attribute__((address_space(3))) void*)lds, 16, 0, 0);
}

// ---------------------------------------------------------------------------
// x: fp32 -> bf16 (A operand of in_proj), 8 elems/thread, 16B stores
// ---------------------------------------------------------------------------
__global__ __launch_bounds__(256) void conv_k(const float* __restrict__ x, u16* __restrict__ xc)
{
    long i = ((long)blockIdx.x * 256 + threadIdx.x) * 8;   // < 4,194,304
    float4 v0 = *reinterpret_cast<const float4*>(x + i);
    float4 v1 = *reinterpret_cast<const float4*>(x + i + 4);
    union { u16 s[8]; u32x4 v; } p;
    p.s[0] = f2b(v0.x); p.s[1] = f2b(v0.y); p.s[2] = f2b(v0.z); p.s[3] = f2b(v0.w);
    p.s[4] = f2b(v1.x); p.s[5] = f2b(v1.y); p.s[6] = f2b(v1.z); p.s[7] = f2b(v1.w);
    *reinterpret_cast<u32x4*>(xc + i) = p.v;
}

// ---------------------------------------------------------------------------
// Weight prep: fp32 -> bf16, TRANSPOSED to [n][k].
// 28 source matrices of 256x256 ([i][o], o contiguous):
//   w in [0,12)  : in_proj (z=k3*4+e)      -> c_ipw_t + w*65536          , ostride 256
//   w in [12,20) : mid (c=(w-12)>>2,e=&3)  -> buf_mw_t + e*131072 + c*256, ostride 512, sign -1 for c=1
//   w in [20,24) : ff_w1 (e)               -> c_fw1_t + e*65536          , ostride 256
//   w in [24,28) : ff_w2 (e)               -> c_fw2_t + e*65536          , ostride 256
// ---------------------------------------------------------------------------
__global__ __launch_bounds__(256) void prep_w(
    const float* __restrict__ ipw, const float* __restrict__ mw,
    const float* __restrict__ fw1, const float* __restrict__ fw2,
    u16* __restrict__ d_ipw, u16* __restrict__ d_mw,
    u16* __restrict__ d_fw1, u16* __restrict__ d_fw2)
{
    __shared__ u16 tile[64][72];
    int blk = blockIdx.x;            // < 448
    int w = blk >> 4, t = blk & 15;
    int tr = (t >> 2) * 64;          // i origin
    int tc = (t & 3) * 64;           // o origin
    const float* src; u16* dst; int ostride; float sign = 1.f;
    if (w < 12)      { src = ipw + (size_t)w * 65536; dst = d_ipw + (size_t)w * 65536; ostride = 256; }
    else if (w < 20) { int u = w - 12, c = u >> 2, e = u & 3;
                       src = mw + (size_t)u * 65536;
                       dst = d_mw + (size_t)e * 131072 + c * 256; ostride = 512;
                       if (c) sign = -1.f; }
    else if (w < 24) { int e = w - 20; src = fw1 + (size_t)e * 65536; dst = d_fw1 + (size_t)e * 65536; ostride = 256; }
    else             { int e = w - 24; src = fw2 + (size_t)e * 65536; dst = d_fw2 + (size_t)e * 65536; ostride = 256; }

    int q = threadIdx.x;
    int r = q >> 2, cb = (q & 3) * 16;
#pragma unroll
    for (int j = 0; j < 4; j++) {
        int col = cb + j * 4;
        const float4 v = *reinterpret_cast<const float4*>(src + (size_t)(tr + r) * 256 + tc + col);
        tile[r][col + 0] = f2b(v.x * sign);
        tile[r][col + 1] = f2b(v.y * sign);
        tile[r][col + 2] = f2b(v.z * sign);
        tile[r][col + 3] = f2b(v.w * sign);
    }
    __syncthreads();
    int ol = q >> 2, ib = (q & 3) * 16;
    union { u16 s[8]; u32x4 v; } p0, p1;
#pragma unroll
    for (int k = 0; k < 8; k++) { p0.s[k] = tile[ib + k][ol]; p1.s[k] = tile[ib + 8 + k][ol]; }
    u16* drow = dst + (size_t)(tc + ol) * ostride + tr + ib;
    *reinterpret_cast<u32x4*>(drow)     = p0.v;
    *reinterpret_cast<u32x4*>(drow + 8) = p1.v;
}

// ---------------------------------------------------------------------------
// Full-LDS GEMM, DOUBLE-BUFFERED (2-phase T3-minimum template):
// C[16384 x 256] = A[M x K] * B^T[N x K].
// Block tile 128 m x 128 n; 4 waves (2x2); wave = 64x64, acc[4][4] (64 regs).
// K-loop in BK=64 steps, LDS double-buffered: per step, issue next tile's
// A/B DMA (global_load_lds) into buf^1 FIRST, then ds_read+32 MFMA from buf,
// then ONE __syncthreads (its vmcnt-0 wait now lands loads that had the
// whole compute phase in flight). r11's single-buffer paid the full L2
// round-trip (~200-900cy) serially per step at only 2 resident blocks/CU.
// Chunk swizzle (8x16B chunks/row): phys = c ^ (row&7); DMA pre-swizzles the
// GLOBAL source chunk (LDS dest stays linear); read side XORs the same mask.
// r11 measured: 0 bank conflicts.
// OPERAND-SWAPPED MFMA: mfma(Bfrag, Afrag) = D^T: lane owns m-row l16 with
// 4 CONSECUTIVE n-cols per acc reg set.
// Epilogue — HW rule (r3/r4/r6/r7): global stores must cover FULL 128-B
// lines within ONE instruction. Per 16-row set, TWO 8-row passes through
// per-wave fs[8][64] f32 (2 KB/wave):
//   write: HALF-WAVE (lanes l16>>3==p) stage 4 acc f32x4, slot
//          phys=(nf*4+quad)^(l16&7)
//   read:  all 64 lanes (row=lane>>3, ch=lane&7), logical slots 2ch,2ch+1
//   store: 16 B/lane, 8 lanes/row -> full 128-B lines. Aux loads 16 B.
// r8 lesson: conditional write + same-address reads across passes lets LLVM
// CSE the reads -> zero-cost asm volatile("" ::: "memory") fences.
// bias/gamma: <=4 named f32x4 regs loaded once (r5 lesson: no arrays).
// REGISTER BUDGET: __launch_bounds__(256,2) -> 256-reg budget, zero spill
// risk (r9 lesson: (256,4)=128 regs spills acc to scratch, +120MB HBM).
// LDS: As 2x16KB + Bs 2x16KB + fs 8KB = 72KB -> 2 blocks/CU (= r11's
// MEASURED residency at 40KB, so no occupancy lost; pipeline gained).
// mode 1: in_proj  z=(k3*4+e): k3<2 -> out0 interleaved *gamma +bias ; k3==2 -> out1 plain +bias
// mode 2: mid      z=e: + (mid_b0-mid_b1) + aux(o) -> out0
// mode 3: ff1      z=e: +bias, exact gelu -> out0
// mode 4: ff2      z=e: +bias + aux(residual) -> out0
// ---------------------------------------------------------------------------
__global__ __launch_bounds__(256, 2) void gemm_k(
    const u16* __restrict__ A0, const u16* __restrict__ B0,
    const float* __restrict__ biasf, const u16* __restrict__ aux,
    const float* __restrict__ gamlogf, u16* __restrict__ out0,
    u16* __restrict__ out1, int K, int mode)
{
    __shared__ __align__(16) u16 As [2 * 128 * 64];  // 32 KB, dbuf [m-row][k-chunk swz]
    __shared__ __align__(16) u16 Bs2[2 * 128 * 64];  // 32 KB, dbuf [n-row][k-chunk swz]
    __shared__ __align__(16) float fs_all[4][512];   // 8 KB, per-wave [8 rows][64 cols] f32

    int tid  = threadIdx.x;
    int wave = tid >> 6, lane = tid & 63;
    int quad = lane >> 4, l16 = lane & 15;
    int wm = wave >> 1, wn = wave & 1;
    int m0 = blockIdx.x * 128, n0 = blockIdx.y * 128;
    int z = blockIdx.z;
    int e, k3 = 0;
    const u16* A;
    const u16* Bm;
    if (mode == 1) { k3 = z >> 2; e = z & 3; A = A0; }
    else           { e = z; A = A0 + (size_t)e * BT_ * K; }
    Bm = B0 + (size_t)(mode == 1 ? z : e) * 256 * K;

    // DMA source setup: each wave stages 32 rows of A and 32 of B per tile
    // (4 instrs x 8 rows). lane l -> row +(l>>3), phys chunk (l&7); global
    // chunk pre-swizzled: (l&7)^(l>>3)  (rowbase % 8 == 0).
    int srow8 = lane >> 3, sch = lane & 7;
    int swc = sch ^ srow8;
    const u16* ag[4]; const u16* bg[4]; int rb[4];
#pragma unroll
    for (int i = 0; i < 4; i++) {
        int ra = wave * 32 + i * 8;
        rb[i] = ra;
        ag[i] = A  + (size_t)(m0 + ra + srow8) * K + swc * 8;
        bg[i] = Bm + (size_t)(n0 + ra + srow8) * K + swc * 8;
    }

    float* fsw = fs_all[wave];
    int rl8 = lane >> 3, ch = lane & 7;

    // readback constants: lane covers cols colb..colb+7 (r5 lesson: no arrays)
    int colb = n0 + wn * 64 + ch * 8;
    f32x4 bias_lo, bias_hi;
    f32x4 gam_lo = (f32x4){1.f, 1.f, 1.f, 1.f}, gam_hi = gam_lo;
    if (mode == 1) {
        bias_lo = *reinterpret_cast<const f32x4*>(biasf + z * 256 + colb);
        bias_hi = *reinterpret_cast<const f32x4*>(biasf + z * 256 + colb + 4);
        if (k3 < 2) {
            f32x4 gl = *reinterpret_cast<const f32x4*>(gamlogf + 2048 + e * 256 + colb);
            f32x4 gh = *reinterpret_cast<const f32x4*>(gamlogf + 2048 + e * 256 + colb + 4);
#pragma unroll
            for (int r = 0; r < 4; r++) { gam_lo[r] = expf(gl[r]); gam_hi[r] = expf(gh[r]); }
        }
    } else if (mode == 2) {
        f32x4 a0 = *reinterpret_cast<const f32x4*>(biasf + e * 256 + colb);
        f32x4 a1 = *reinterpret_cast<const f32x4*>(biasf + e * 256 + colb + 4);
        f32x4 c0 = *reinterpret_cast<const f32x4*>(biasf + 1024 + e * 256 + colb);
        f32x4 c1 = *reinterpret_cast<const f32x4*>(biasf + 1024 + e * 256 + colb + 4);
        bias_lo = a0 - c0; bias_hi = a1 - c1;
    } else {
        bias_lo = *reinterpret_cast<const f32x4*>(biasf + e * 256 + colb);
        bias_hi = *reinterpret_cast<const f32x4*>(biasf + e * 256 + colb + 4);
    }

    f32x4 acc[4][4];
#pragma unroll
    for (int i = 0; i < 4; i++)
#pragma unroll
        for (int j = 0; j < 4; j++) acc[i][j] = (f32x4){0.f, 0.f, 0.f, 0.f};

    int nstep = K >> 6;

    // prologue: stage tile 0 into buffer 0
#pragma unroll
    for (int i = 0; i < 4; i++) {
        gload_lds16(ag[i], As  + rb[i] * 64);
        gload_lds16(bg[i], Bs2 + rb[i] * 64);
        ag[i] += 64; bg[i] += 64;
    }
    __syncthreads();                             // tile 0 landed

    for (int st = 0; st < nstep; ++st) {
        int cur = st & 1;
        const u16* Ab = As  + cur * 8192;
        const u16* Bb = Bs2 + cur * 8192;
        if (st + 1 < nstep) {                    // issue next tile FIRST
            int nx = cur ^ 1;
#pragma unroll
            for (int i = 0; i < 4; i++) {
                gload_lds16(ag[i], As  + nx * 8192 + rb[i] * 64);
                gload_lds16(bg[i], Bs2 + nx * 8192 + rb[i] * 64);
                ag[i] += 64; bg[i] += 64;
            }
        }

#pragma unroll
        for (int kt = 0; kt < 2; kt++) {
            bf16x8 afr[4], bfr[4];
#pragma unroll
            for (int f = 0; f < 4; f++) {
                int phys = (kt * 4 + quad) ^ (l16 & 7);
                int rowa = wm * 64 + f * 16 + l16;
                int rowb = wn * 64 + f * 16 + l16;
                union { u32x4 v; bf16x8 b; } u, w;
                u.v = *reinterpret_cast<const u32x4*>(Ab + rowa * 64 + phys * 8);
                w.v = *reinterpret_cast<const u32x4*>(Bb + rowb * 64 + phys * 8);
                afr[f] = u.b; bfr[f] = w.b;
            }
            // swapped operands: D^T — lane = m-row, regs = 4 consecutive n-cols
#pragma unroll
            for (int i = 0; i < 4; i++)
#pragma unroll
                for (int j = 0; j < 4; j++)
                    acc[i][j] = __builtin_amdgcn_mfma_f32_16x16x32_bf16(bfr[j], afr[i], acc[i][j], 0, 0, 0);
        }
        if (st + 1 < nstep) __syncthreads();     // next tile landed; cur free
    }

    // epilogue: per 16-row set s, two 8-row passes through fs[8][64]
#pragma unroll
    for (int s = 0; s < 4; s++) {
#pragma unroll
        for (int p = 0; p < 2; p++) {
            if ((l16 >> 3) == p) {
#pragma unroll
                for (int nf = 0; nf < 4; nf++) {
                    int phys = (nf * 4 + quad) ^ (l16 & 7);
                    *reinterpret_cast<f32x4*>(fsw + (l16 & 7) * 64 + phys * 4) = acc[s][nf];
                }
            }
            // compiler fence: forbid CSE/reorder of the cross-lane LDS
            // exchange (r8 failure); emits no instruction.
            asm volatile("" ::: "memory");
            int pa = (2 * ch) ^ rl8;
            f32x4 lo = *reinterpret_cast<const f32x4*>(fsw + rl8 * 64 + pa * 4);
            f32x4 hi = *reinterpret_cast<const f32x4*>(fsw + rl8 * 64 + (pa ^ 1) * 4);
            asm volatile("" ::: "memory");
            lo += bias_lo; hi += bias_hi;
            if (mode == 1) { lo *= gam_lo; hi *= gam_hi; }
            if (mode == 3) {
#pragma unroll
                for (int r = 0; r < 4; r++) {
                    lo[r] = 0.5f * lo[r] * (1.0f + erff(lo[r] * 0.70710678118654752f));
                    hi[r] = 0.5f * hi[r] * (1.0f + erff(hi[r] * 0.70710678118654752f));
                }
            }
            int grow = m0 + wm * 64 + s * 16 + p * 8 + rl8;
            u16* dstp;
            if (mode == 1) {
                if (k3 < 2) dstp = out0 + (((size_t)(e * BT_ + grow)) * 2 + k3) * 256 + colb;
                else        dstp = out1 + ((size_t)e * BT_ + grow) * 256 + colb;
            } else {
                dstp = out0 + ((size_t)e * BT_ + grow) * 256 + colb;
            }
            if (mode == 2 || mode == 4) {
                const u16* ap = aux + ((size_t)e * BT_ + grow) * 256 + colb;
                u32x4 av = *reinterpret_cast<const u32x4*>(ap);
                lo[0] += b2f((u16)(av[0] & 0xffffu)); lo[1] += b2f((u16)(av[0] >> 16));
                lo[2] += b2f((u16)(av[1] & 0xffffu)); lo[3] += b2f((u16)(av[1] >> 16));
                hi[0] += b2f((u16)(av[2] & 0xffffu)); hi[1] += b2f((u16)(av[2] >> 16));
                hi[2] += b2f((u16)(av[3] & 0xffffu)); hi[3] += b2f((u16)(av[3] >> 16));
            }
            u32x4 pv;
            pv[0] = (unsigned int)f2b(lo[0]) | ((unsigned int)f2b(lo[1]) << 16);
            pv[1] = (unsigned int)f2b(lo[2]) | ((unsigned int)f2b(lo[3]) << 16);
            pv[2] = (unsigned int)f2b(hi[0]) | ((unsigned int)f2b(hi[1]) << 16);
            pv[3] = (unsigned int)f2b(hi[2]) | ((unsigned int)f2b(hi[3]) << 16);
            *reinterpret_cast<u32x4*>(dstp) = pv;
        }
    }
}

// ---------------------------------------------------------------------------
// LRU scan, 3 phases, 2 d-lanes per thread (u32 loads/stores).
// buf_u layout: ((e*BT + b*T + t)*2 + c)*256 + d  (c=0:re, 1:im)
// ---------------------------------------------------------------------------
__global__ __launch_bounds__(256) void scan_a(const u16* __restrict__ u,
    const float* __restrict__ plog, float2* __restrict__ carry)
{
    int l2 = blockIdx.x * 256 + threadIdx.x;      // < 8192
    int chunk = blockIdx.y;
    int dd = (l2 & 127) * 2, b = (l2 >> 7) & 15, e = l2 >> 11;
    float nu0 = expf(plog[e * 256 + dd]),        nu1 = expf(plog[e * 256 + dd + 1]);
    float th0 = expf(plog[1024 + e * 256 + dd]), th1 = expf(plog[1024 + e * 256 + dd + 1]);
    float m0 = expf(-nu0), m1 = expf(-nu1);
    float fr0 = m0 * cosf(th0), fi0 = m0 * sinf(th0);
    float fr1 = m1 * cosf(th1), fi1 = m1 * sinf(th1);
    size_t base = ((size_t)e * BT_ + b * TT) * 512 + (size_t)chunk * CLEN * 512 + dd;
    float hr0 = 0.f, hi0 = 0.f, hr1 = 0.f, hi1 = 0.f;
    for (int t = 0; t < CLEN; t++) {
        unsigned int wr = *reinterpret_cast<const unsigned int*>(u + base);
        unsigned int wi = *reinterpret_cast<const unsigned int*>(u + base + 256);
        float ur0 = b2f((u16)wr), ur1 = b2f((u16)(wr >> 16));
        float ui0 = b2f((u16)wi), ui1 = b2f((u16)(wi >> 16));
        float a0 = fr0 * hr0 - fi0 * hi0 + ur0;
        float b0 = fr0 * hi0 + fi0 * hr0 + ui0;
        float a1 = fr1 * hr1 - fi1 * hi1 + ur1;
        float b1 = fr1 * hi1 + fi1 * hr1 + ui1;
        hr0 = a0; hi0 = b0; hr1 = a1; hi1 = b1;
        base += 512;
    }
    size_t ci = (size_t)chunk * LANES + (size_t)e * 4096 + b * 256 + dd;
    *reinterpret_cast<float4*>(&carry[ci]) = make_float4(hr0, hi0, hr1, hi1);
}

__global__ __launch_bounds__(256) void scan_b(const float* __restrict__ plog,
                                              float2* __restrict__ carry)
{
    int l = blockIdx.x * 256 + threadIdx.x;
    int d = l & 255, e = l >> 12;
    float nu = expf(plog[e * 256 + d]);
    float th = expf(plog[1024 + e * 256 + d]);
    float magL = expf(-nu * (float)CLEN);
    float ang = th * (float)CLEN;
    float frL = magL * cosf(ang), fiL = magL * sinf(ang);
    float gr = 0.f, gi = 0.f;
    for (int j = 0; j < CHUNKS; j++) {
        float2 c = carry[(size_t)j * LANES + l];
        carry[(size_t)j * LANES + l] = make_float2(gr, gi);
        float gr2 = frL * gr - fiL * gi + c.x;
        float gi2 = frL * gi + fiL * gr + c.y;
        gr = gr2; gi = gi2;
    }
}

// scan_c also writes hidden (fp32, exact) on the last chunk.
__global__ __launch_bounds__(256) void scan_c(u16* __restrict__ u,
    const float* __restrict__ plog, const float2* __restrict__ carry,
    float* __restrict__ outh)
{
    int l2 = blockIdx.x * 256 + threadIdx.x;      // < 8192
    int chunk = blockIdx.y;
    int dd = (l2 & 127) * 2, b = (l2 >> 7) & 15, e = l2 >> 11;
    float nu0 = expf(plog[e * 256 + dd]),        nu1 = expf(plog[e * 256 + dd + 1]);
    float th0 = expf(plog[1024 + e * 256 + dd]), th1 = expf(plog[1024 + e * 256 + dd + 1]);
    float m0 = expf(-nu0), m1 = expf(-nu1);
    float fr0 = m0 * cosf(th0), fi0 = m0 * sinf(th0);
    float fr1 = m1 * cosf(th1), fi1 = m1 * sinf(th1);
    size_t base = ((size_t)e * BT_ + b * TT) * 512 + (size_t)chunk * CLEN * 512 + dd;
    size_t ci = (size_t)chunk * LANES + (size_t)e * 4096 + b * 256 + dd;
    float4 c0 = *reinterpret_cast<const float4*>(&carry[ci]);
    float hr0 = c0.x, hi0 = c0.y, hr1 = c0.z, hi1 = c0.w;
    for (int t = 0; t < CLEN; t++) {
        unsigned int wr = *reinterpret_cast<const unsigned int*>(u + base);
        unsigned int wi = *reinterpret_cast<const unsigned int*>(u + base + 256);
        float ur0 = b2f((u16)wr), ur1 = b2f((u16)(wr >> 16));
        float ui0 = b2f((u16)wi), ui1 = b2f((u16)(wi >> 16));
        float a0 = fr0 * hr0 - fi0 * hi0 + ur0;
        float b0 = fr0 * hi0 + fi0 * hr0 + ui0;
        float a1 = fr1 * hr1 - fi1 * hi1 + ur1;
        float b1 = fr1 * hi1 + fi1 * hr1 + ui1;
        hr0 = a0; hi0 = b0; hr1 = a1; hi1 = b1;
        *reinterpret_cast<unsigned int*>(u + base) =
            (unsigned int)f2b(hr0) | ((unsigned int)f2b(hr1) << 16);
        *reinterpret_cast<unsigned int*>(u + base + 256) =
            (unsigned int)f2b(hi0) | ((unsigned int)f2b(hi1) << 16);
        base += 512;
    }
    if (chunk == CHUNKS - 1) {
        float* oh = outh + (size_t)4 * BT_ * 256;
        *reinterpret_cast<float2*>(&oh[b * 2048 + e * 256 + dd])        = make_float2(hr0, hr1);
        *reinterpret_cast<float2*>(&oh[b * 2048 + 1024 + e * 256 + dd]) = make_float2(hi0, hi1);
    }
}

// LayerNorm across (e,d) per row r=(b,t); h2 plain (E, BT, D) bf16; fp32 out
__global__ __launch_bounds__(256) void ln_k(const u16* __restrict__ h2,
    const float* __restrict__ lnw, const float* __restrict__ lnb,
    float* __restrict__ out)
{
    int r = blockIdx.x;
    int d = threadIdx.x;
    float v[4]; float s1 = 0.f, s2 = 0.f;
#pragma unroll
    for (int e = 0; e < 4; e++) {
        float x = b2f(h2[((size_t)e * BT_ + r) * 256 + d]);
        v[e] = x; s1 += x; s2 += x * x;
    }
#pragma unroll
    for (int off = 32; off; off >>= 1) {
        s1 += __shfl_down(s1, off, 64);
        s2 += __shfl_down(s2, off, 64);
    }
    __shared__ float sm[8];
    int wave = threadIdx.x >> 6, lane = threadIdx.x & 63;
    if (lane == 0) { sm[wave] = s1; sm[4 + wave] = s2; }
    __syncthreads();
    float S1 = sm[0] + sm[1] + sm[2] + sm[3];
    float S2 = sm[4] + sm[5] + sm[6] + sm[7];
    float mean = S1 * (1.0f / 1024.0f);
    float var = S2 * (1.0f / 1024.0f) - mean * mean;
    float rstd = rsqrtf(var + 1e-5f);
#pragma unroll
    for (int e = 0; e < 4; e++) {
        float o = (v[e] - mean) * rstd * lnw[e * 256 + d] + lnb[e * 256 + d];
        out[((size_t)e * BT_ + r) * 256 + d] = o;
    }
}

extern "C" void kernel_launch(void* const* d_in, const int* in_sizes, int n_in,
                              void* d_out, int out_size, void* d_ws, size_t ws_size,
                              hipStream_t stream)
{
    const float* x    = (const float*)d_in[0];
    const float* ipw  = (const float*)d_in[1];
    const float* ipb  = (const float*)d_in[2];
    const float* plog = (const float*)d_in[3];
    const float* mw   = (const float*)d_in[4];
    const float* mb   = (const float*)d_in[5];
    const float* fw1  = (const float*)d_in[6];
    const float* fb1  = (const float*)d_in[7];
    const float* fw2  = (const float*)d_in[8];
    const float* fb2  = (const float*)d_in[9];
    const float* lnw  = (const float*)d_in[10];
    const float* lnb  = (const float*)d_in[11];
    float* out = (float*)d_out;

    // Workspace (u16 elem offsets; ~99.5 MiB):
    //   buf_u    [0,          33,554,432)  scan buffer (E,BT,2,D) bf16, later h2
    //   buf_out  [33,554,432, 50,331,648)  mid output bf16; ALIASED early by:
    //              xc (bf16 x, 4,194,304) at 33,554,432   [dead after in_proj]
    //              carry (float2, 4 MiB)  at 37,748,736   [dead after scan_c]
    //   buf_mw_t [50,331,648, 50,855,936)  [e][o][c*256+d] stacked, sign-folded
    //   c_ipw_t  [50,855,936, 51,642,368)  [z][o][i]
    //   c_fw1_t  [51,642,368, 51,904,512)  [e][o][d]
    //   c_fw2_t  [51,904,512, 52,166,656)  [e][o][d]
    // d_out bytes [0, 33.5 MB) double as bf16 scratch for `o` then `h1`.
    u16* W = (u16*)d_ws;
    u16* buf_u    = W;
    u16* buf_out  = W + (size_t)33554432;
    u16* xc       = W + (size_t)33554432;
    float2* carry = (float2*)(W + (size_t)37748736);
    u16* buf_mw_t = W + (size_t)50331648;
    u16* c_ipw_t  = W + (size_t)50855936;
    u16* c_fw1_t  = W + (size_t)51642368;
    u16* c_fw2_t  = W + (size_t)51904512;
    u16* scratch  = (u16*)d_out;

    conv_k<<<2048, 256, 0, stream>>>(x, xc);
    prep_w<<<448, 256, 0, stream>>>(ipw, mw, fw1, fw2, c_ipw_t, buf_mw_t, c_fw1_t, c_fw2_t);
    // in_proj: u0,u1 (gamma-scaled, interleaved) -> buf_u ; o -> d_out scratch
    gemm_k<<<dim3(128, 2, 12), 256, 0, stream>>>(xc, c_ipw_t, ipb, nullptr, plog, buf_u, scratch, 256, 1);
    // LRU scan (chunked, 3 phases), in-place in buf_u (xc dead now); hidden fused into scan_c
    scan_a<<<dim3(32, CHUNKS), 256, 0, stream>>>(buf_u, plog, carry);
    scan_b<<<64, 256, 0, stream>>>(plog, carry);
    scan_c<<<dim3(32, CHUNKS), 256, 0, stream>>>(buf_u, plog, carry, out);
    // mid (K=512 fused r/i) + o -> buf_out   (carry dead now)
    gemm_k<<<dim3(128, 2, 4), 256, 0, stream>>>(buf_u, buf_mw_t, mb, scratch, nullptr, buf_out, nullptr, 512, 2);
    // ff1 + gelu -> d_out scratch (h1; `o` dead)
    gemm_k<<<dim3(128, 2, 4), 256, 0, stream>>>(buf_out, c_fw1_t, fb1, nullptr, nullptr, scratch, nullptr, 256, 3);
    // ff2 + residual -> buf_u (h2 plain; scan data dead)
    gemm_k<<<dim3(128, 2, 4), 256, 0, stream>>>(scratch, c_fw2_t, fb2, buf_out, nullptr, buf_u, nullptr, 256, 4);
    // layernorm across (e,d) -> d_out fp32 (overwrites scratch region last)
    ln_k<<<16384, 256, 0, stream>>>(buf_u, lnw, lnb, out);
}